// Round 3
// baseline (642.005 us; speedup 1.0000x reference)
//
#include <hip/hip_runtime.h>
#include <hip/hip_fp16.h>

#define N_NODES 100000
#define N_EDGES 1600000
#define SCAN_BLOCKS 196   // 196*512 = 100352 >= N_NODES
#define BSHIFT 5
#define NBUCKET ((N_NODES + 31) >> BSHIFT)   // 3125

// ---------------------------------------------------------------------------
// CSR build: histogram -> exclusive scan -> binned two-pass fill
// ---------------------------------------------------------------------------
__global__ __launch_bounds__(256) void k_hist(
    const int* __restrict__ ei, int* __restrict__ counts)
{
    int e = blockIdx.x * 256 + threadIdx.x;
    if (e < N_EDGES) atomicAdd(&counts[ei[N_EDGES + e]], 1);
}

__global__ __launch_bounds__(512) void k_scan1(
    const int* __restrict__ counts, int* __restrict__ row_ptr,
    int* __restrict__ blockSums)
{
    __shared__ int s[512];
    int t = threadIdx.x;
    int i = blockIdx.x * 512 + t;
    int c = (i < N_NODES) ? counts[i] : 0;
    s[t] = c;
    __syncthreads();
    #pragma unroll
    for (int off = 1; off < 512; off <<= 1) {
        int v = (t >= off) ? s[t - off] : 0;
        __syncthreads();
        s[t] += v;
        __syncthreads();
    }
    if (i < N_NODES) row_ptr[i] = s[t] - c;
    if (t == 511) blockSums[blockIdx.x] = s[511];
}

__global__ __launch_bounds__(256) void k_scan2(int* __restrict__ blockSums)
{
    __shared__ int s[256];
    int t = threadIdx.x;
    int c = (t < SCAN_BLOCKS) ? blockSums[t] : 0;
    s[t] = c;
    __syncthreads();
    #pragma unroll
    for (int off = 1; off < 256; off <<= 1) {
        int v = (t >= off) ? s[t - off] : 0;
        __syncthreads();
        s[t] += v;
        __syncthreads();
    }
    if (t < SCAN_BLOCKS) blockSums[t] = s[t] - c;
}

__global__ __launch_bounds__(512) void k_scan3(
    int* __restrict__ row_ptr, const int* __restrict__ blockSums,
    int* __restrict__ cursor)
{
    int i = blockIdx.x * 512 + threadIdx.x;
    if (i < N_NODES) {
        int v = row_ptr[i] + blockSums[blockIdx.x];
        row_ptr[i] = v;
        cursor[i]  = v;
    }
    if (i == 0) row_ptr[N_NODES] = N_EDGES;
}

// bucket cursors: bucket b covers nodes [b*32,(b+1)*32) -> csr range starts
// at row_ptr[b*32] (valid only after k_scan3)
__global__ __launch_bounds__(256) void k_bcur(
    const int* __restrict__ row_ptr, int* __restrict__ bcur)
{
    int b = blockIdx.x * 256 + threadIdx.x;
    if (b < NBUCKET) bcur[b] = row_ptr[b << BSHIFT];
}

// pass A: coarse scatter into dst-range buckets (write-locality: cursors are
// sequential per bucket, lines complete before eviction)
__global__ __launch_bounds__(256) void k_binA(
    const int* __restrict__ ei, int* __restrict__ bcur,
    int2* __restrict__ ebuf)
{
    int e = blockIdx.x * 256 + threadIdx.x;
    if (e < N_EDGES) {
        int src = ei[e];
        int dst = ei[N_EDGES + e];
        int pos = atomicAdd(&bcur[dst >> BSHIFT], 1);
        ebuf[pos] = make_int2(src, dst);
    }
}

// pass B: fine fill; writes for one bucket span only ~deg*32 entries (~2 KB)
__global__ __launch_bounds__(256) void k_fillB(
    const int2* __restrict__ ebuf, int* __restrict__ cursor,
    int* __restrict__ csr_src)
{
    int i = blockIdx.x * 256 + threadIdx.x;
    if (i < N_EDGES) {
        int2 sd = ebuf[i];
        int pos = atomicAdd(&cursor[sd.y], 1);
        csr_src[pos] = sd.x;
    }
}

// ---------------------------------------------------------------------------
// x (fp32) -> x_h (fp16), streaming
// ---------------------------------------------------------------------------
__global__ __launch_bounds__(256) void k_tohalf(
    const float* __restrict__ x, __half* __restrict__ x_h)
{
    int i = blockIdx.x * 256 + threadIdx.x;   // one float4 -> 4 halves
    if (i < N_NODES * 32) {
        float4 v = ((const float4*)x)[i];
        __half2 a = __floats2half2_rn(v.x, v.y);
        __half2 b = __floats2half2_rn(v.z, v.w);
        uint2 u = make_uint2(*(unsigned*)&a, *(unsigned*)&b);
        ((uint2*)x_h)[i] = u;
    }
}

// ---------------------------------------------------------------------------
// K-agg1: agg[n] = sum_{e in row n} x_h[csr_src[e]]  (fp16 gather, fp32 acc)
// 32 lanes per node (8 B = 4 ch per lane), 8 nodes per 256-block, 4x unroll.
// ---------------------------------------------------------------------------
__device__ __forceinline__ void acc_row_h(
    const __half* __restrict__ x_h, int s, int lane, float4& acc)
{
    uint2 u = ((const uint2*)(x_h + (size_t)s * 128))[lane];
    __half2 a = *(__half2*)&u.x;
    __half2 b = *(__half2*)&u.y;
    float2 fa = __half22float2(a);
    float2 fb = __half22float2(b);
    acc.x += fa.x; acc.y += fa.y; acc.z += fb.x; acc.w += fb.y;
}

__global__ __launch_bounds__(256) void k_agg1(
    const int* __restrict__ row_ptr, const int* __restrict__ csr_src,
    const __half* __restrict__ x_h, float* __restrict__ agg)
{
    int tid  = threadIdx.x;
    int n    = blockIdx.x * 8 + (tid >> 5);
    int lane = tid & 31;
    int e0 = row_ptr[n], e1 = row_ptr[n + 1];
    float4 acc = make_float4(0.f, 0.f, 0.f, 0.f);
    int e = e0;
    for (; e + 4 <= e1; e += 4) {
        int s0 = csr_src[e], s1 = csr_src[e + 1];
        int s2 = csr_src[e + 2], s3 = csr_src[e + 3];
        acc_row_h(x_h, s0, lane, acc);
        acc_row_h(x_h, s1, lane, acc);
        acc_row_h(x_h, s2, lane, acc);
        acc_row_h(x_h, s3, lane, acc);
    }
    for (; e < e1; ++e) acc_row_h(x_h, csr_src[e], lane, acc);
    ((float4*)agg)[n * 32 + lane] = acc;
}

// ---------------------------------------------------------------------------
// K2: h = relu(bn( (agg/deg) @ W1l^T + b1l + x @ W1r^T ))
// ---------------------------------------------------------------------------
__global__ __launch_bounds__(256) void k_gemm1(
    const float* __restrict__ agg, const int* __restrict__ row_ptr,
    const float* __restrict__ x,
    const float* __restrict__ W1l, const float* __restrict__ b1l,
    const float* __restrict__ W1r,
    const float* __restrict__ gamma, const float* __restrict__ beta,
    const float* __restrict__ mean, const float* __restrict__ var,
    float* __restrict__ h)
{
    __shared__ float As[64][36];
    __shared__ float Bs[32][132];
    int tid = threadIdx.x;
    int n0  = blockIdx.x * 64;
    int tx  = tid & 15, ty = tid >> 4;
    int lrow = tid >> 3;
    int lkq  = (tid & 7) * 4;
    float acc[4][8];
    #pragma unroll
    for (int i = 0; i < 4; ++i)
        #pragma unroll
        for (int j = 0; j < 8; ++j) acc[i][j] = 0.f;

    for (int kt = 0; kt < 256; kt += 32) {
        #pragma unroll
        for (int p = 0; p < 2; ++p) {
            int r = lrow + p * 32;
            int n = n0 + r;
            int k = kt + lkq;
            float4 v = make_float4(0.f, 0.f, 0.f, 0.f);
            if (n < N_NODES) {
                if (k < 128) {
                    v = *(const float4*)(agg + n * 128 + k);
                    float d = (float)(row_ptr[n + 1] - row_ptr[n]);
                    float inv = 1.0f / fmaxf(d, 1.0f);
                    v.x *= inv; v.y *= inv; v.z *= inv; v.w *= inv;
                } else {
                    v = *(const float4*)(x + n * 128 + (k - 128));
                }
            }
            *(float4*)&As[r][lkq] = v;
        }
        #pragma unroll
        for (int p = 0; p < 4; ++p) {
            int j = lrow + p * 32;
            int k = kt + lkq;
            const float* W = (k < 128) ? (W1l + j * 128 + k)
                                       : (W1r + j * 128 + (k - 128));
            float4 v = *(const float4*)W;
            Bs[lkq + 0][j] = v.x;
            Bs[lkq + 1][j] = v.y;
            Bs[lkq + 2][j] = v.z;
            Bs[lkq + 3][j] = v.w;
        }
        __syncthreads();
        #pragma unroll
        for (int kk = 0; kk < 32; ++kk) {
            float a[4];
            #pragma unroll
            for (int i = 0; i < 4; ++i) a[i] = As[ty * 4 + i][kk];
            float4 b0 = *(const float4*)&Bs[kk][tx * 8];
            float4 b1 = *(const float4*)&Bs[kk][tx * 8 + 4];
            #pragma unroll
            for (int i = 0; i < 4; ++i) {
                acc[i][0] += a[i] * b0.x; acc[i][1] += a[i] * b0.y;
                acc[i][2] += a[i] * b0.z; acc[i][3] += a[i] * b0.w;
                acc[i][4] += a[i] * b1.x; acc[i][5] += a[i] * b1.y;
                acc[i][6] += a[i] * b1.z; acc[i][7] += a[i] * b1.w;
            }
        }
        __syncthreads();
    }
    float sj[8], tj[8];
    #pragma unroll
    for (int jj = 0; jj < 8; ++jj) {
        int j = tx * 8 + jj;
        float s = gamma[j] * rsqrtf(var[j] + 1e-5f);
        sj[jj] = s;
        tj[jj] = beta[j] + (b1l[j] - mean[j]) * s;
    }
    #pragma unroll
    for (int i = 0; i < 4; ++i) {
        int n = n0 + ty * 4 + i;
        if (n < N_NODES) {
            float o[8];
            #pragma unroll
            for (int jj = 0; jj < 8; ++jj)
                o[jj] = fmaxf(acc[i][jj] * sj[jj] + tj[jj], 0.f);
            *(float4*)(h + n * 128 + tx * 8)     = make_float4(o[0], o[1], o[2], o[3]);
            *(float4*)(h + n * 128 + tx * 8 + 4) = make_float4(o[4], o[5], o[6], o[7]);
        }
    }
}

// ---------------------------------------------------------------------------
// K3: p2 = h @ W2l^T (fp16, for the gather) ; out = h @ W2r^T + b2l (fp32)
// ---------------------------------------------------------------------------
__global__ __launch_bounds__(256) void k_gemm2(
    const float* __restrict__ h,
    const float* __restrict__ W2l, const float* __restrict__ b2l,
    const float* __restrict__ W2r,
    __half* __restrict__ p2, float* __restrict__ out)
{
    __shared__ float As[64][36];
    __shared__ float Bs[32][132];
    int tid = threadIdx.x;
    int n0  = blockIdx.x * 64;
    int tx  = tid & 15, ty = tid >> 4;
    int lrow = tid >> 3;
    int lkq  = (tid & 7) * 4;
    float acc[4][8];
    #pragma unroll
    for (int i = 0; i < 4; ++i)
        #pragma unroll
        for (int j = 0; j < 8; ++j) acc[i][j] = 0.f;

    for (int kt = 0; kt < 128; kt += 32) {
        #pragma unroll
        for (int p = 0; p < 2; ++p) {
            int r = lrow + p * 32;
            int n = n0 + r;
            float4 v = make_float4(0.f, 0.f, 0.f, 0.f);
            if (n < N_NODES) v = *(const float4*)(h + n * 128 + kt + lkq);
            *(float4*)&As[r][lkq] = v;
        }
        #pragma unroll
        for (int p = 0; p < 4; ++p) {
            int j = lrow + p * 32;
            int k = kt + lkq;
            const float* W = (j < 64) ? (W2l + j * 128 + k)
                                      : (W2r + (j - 64) * 128 + k);
            float4 v = *(const float4*)W;
            Bs[lkq + 0][j] = v.x;
            Bs[lkq + 1][j] = v.y;
            Bs[lkq + 2][j] = v.z;
            Bs[lkq + 3][j] = v.w;
        }
        __syncthreads();
        #pragma unroll
        for (int kk = 0; kk < 32; ++kk) {
            float a[4];
            #pragma unroll
            for (int i = 0; i < 4; ++i) a[i] = As[ty * 4 + i][kk];
            float4 b0 = *(const float4*)&Bs[kk][tx * 8];
            float4 b1 = *(const float4*)&Bs[kk][tx * 8 + 4];
            #pragma unroll
            for (int i = 0; i < 4; ++i) {
                acc[i][0] += a[i] * b0.x; acc[i][1] += a[i] * b0.y;
                acc[i][2] += a[i] * b0.z; acc[i][3] += a[i] * b0.w;
                acc[i][4] += a[i] * b1.x; acc[i][5] += a[i] * b1.y;
                acc[i][6] += a[i] * b1.z; acc[i][7] += a[i] * b1.w;
            }
        }
        __syncthreads();
    }
    if (tx < 8) {
        // p2 (fp16): 8 halves = 16 B per thread
        #pragma unroll
        for (int i = 0; i < 4; ++i) {
            int n = n0 + ty * 4 + i;
            if (n < N_NODES) {
                __half2 h0 = __floats2half2_rn(acc[i][0], acc[i][1]);
                __half2 h1 = __floats2half2_rn(acc[i][2], acc[i][3]);
                __half2 h2 = __floats2half2_rn(acc[i][4], acc[i][5]);
                __half2 h3 = __floats2half2_rn(acc[i][6], acc[i][7]);
                uint4 u = make_uint4(*(unsigned*)&h0, *(unsigned*)&h1,
                                     *(unsigned*)&h2, *(unsigned*)&h3);
                *((uint4*)(p2 + (size_t)n * 64) + tx) = u;
            }
        }
    } else {
        int jb = (tx - 8) * 8;
        float bb[8];
        #pragma unroll
        for (int jj = 0; jj < 8; ++jj) bb[jj] = b2l[jb + jj];
        #pragma unroll
        for (int i = 0; i < 4; ++i) {
            int n = n0 + ty * 4 + i;
            if (n < N_NODES) {
                *(float4*)(out + n * 64 + jb)     = make_float4(acc[i][0] + bb[0], acc[i][1] + bb[1], acc[i][2] + bb[2], acc[i][3] + bb[3]);
                *(float4*)(out + n * 64 + jb + 4) = make_float4(acc[i][4] + bb[4], acc[i][5] + bb[5], acc[i][6] + bb[6], acc[i][7] + bb[7]);
            }
        }
    }
}

// ---------------------------------------------------------------------------
// K-agg2: out[n] += (sum_{e in row n} p2[csr_src[e]]) / max(deg,1)
// 16 lanes per node (8 B = 4 ch per lane), fp16 gather, fp32 acc, 4x unroll.
// ---------------------------------------------------------------------------
__device__ __forceinline__ void acc_row_p2(
    const __half* __restrict__ p2, int s, int lane, float4& acc)
{
    uint2 u = ((const uint2*)(p2 + (size_t)s * 64))[lane];
    __half2 a = *(__half2*)&u.x;
    __half2 b = *(__half2*)&u.y;
    float2 fa = __half22float2(a);
    float2 fb = __half22float2(b);
    acc.x += fa.x; acc.y += fa.y; acc.z += fb.x; acc.w += fb.y;
}

__global__ __launch_bounds__(256) void k_agg2(
    const int* __restrict__ row_ptr, const int* __restrict__ csr_src,
    const __half* __restrict__ p2, float* __restrict__ out)
{
    int tid  = threadIdx.x;
    int n    = blockIdx.x * 16 + (tid >> 4);
    int lane = tid & 15;
    int e0 = row_ptr[n], e1 = row_ptr[n + 1];
    float4 acc = make_float4(0.f, 0.f, 0.f, 0.f);
    int e = e0;
    for (; e + 4 <= e1; e += 4) {
        int s0 = csr_src[e], s1 = csr_src[e + 1];
        int s2 = csr_src[e + 2], s3 = csr_src[e + 3];
        acc_row_p2(p2, s0, lane, acc);
        acc_row_p2(p2, s1, lane, acc);
        acc_row_p2(p2, s2, lane, acc);
        acc_row_p2(p2, s3, lane, acc);
    }
    for (; e < e1; ++e) acc_row_p2(p2, csr_src[e], lane, acc);
    float inv = 1.0f / fmaxf((float)(e1 - e0), 1.0f);
    float4* o = (float4*)out + n * 16 + lane;
    float4 cur = *o;
    cur.x += acc.x * inv; cur.y += acc.y * inv;
    cur.z += acc.z * inv; cur.w += acc.w * inv;
    *o = cur;
}

// ---------------------------------------------------------------------------
extern "C" void kernel_launch(void* const* d_in, const int* in_sizes, int n_in,
                              void* d_out, int out_size, void* d_ws, size_t ws_size,
                              hipStream_t stream)
{
    const float* x     = (const float*)d_in[0];
    const int*   ei    = (const int*)d_in[1];
    const float* W1l   = (const float*)d_in[2];
    const float* b1l   = (const float*)d_in[3];
    const float* W1r   = (const float*)d_in[4];
    const float* gamma = (const float*)d_in[5];
    const float* beta  = (const float*)d_in[6];
    const float* mean  = (const float*)d_in[7];
    const float* var   = (const float*)d_in[8];
    const float* W2l   = (const float*)d_in[9];
    const float* b2l   = (const float*)d_in[10];
    const float* W2r   = (const float*)d_in[11];
    float* out = (float*)d_out;

    char* ws = (char*)d_ws;
    float*  agg1    = (float*)ws;                    // 51.2 MB; reused as p2 (fp16, 12.8 MB)
    char*   hreg    = ws + 51200000;                 // 51.2 MB region for h
    float*  h       = (float*)hreg;
    // CSR-build temporaries + x_h alias the h region (all dead before k_gemm1):
    int*    counts  = (int*)hreg;                    // 400 KB
    int*    cursor  = (int*)(hreg + 400000);         // 400 KB
    int2*   ebuf    = (int2*)(hreg + 800000);        // 12.8 MB
    __half* x_h     = (__half*)(hreg + 13600000);    // 25.6 MB (ends 39.2 MB)
    int*    row_ptr = (int*)(ws + 102400000);        // 400 KB + 4
    int*    csr_src = (int*)(ws + 102800640);        // 6.4 MB
    int*    blockSums = (int*)(ws + 109200640);      // 1 KB
    int*    bcur    = (int*)(ws + 109201664);        // 12.5 KB
    __half* p2      = (__half*)agg1;

    hipMemsetAsync(counts, 0, N_NODES * sizeof(int), stream);
    k_hist<<<(N_EDGES + 255) / 256, 256, 0, stream>>>(ei, counts);
    k_tohalf<<<(N_NODES * 32 + 255) / 256, 256, 0, stream>>>(x, x_h);
    k_scan1<<<SCAN_BLOCKS, 512, 0, stream>>>(counts, row_ptr, blockSums);
    k_scan2<<<1, 256, 0, stream>>>(blockSums);
    k_scan3<<<SCAN_BLOCKS, 512, 0, stream>>>(row_ptr, blockSums, cursor);
    k_bcur<<<(NBUCKET + 255) / 256, 256, 0, stream>>>(row_ptr, bcur);
    k_binA<<<(N_EDGES + 255) / 256, 256, 0, stream>>>(ei, bcur, ebuf);
    k_fillB<<<(N_EDGES + 255) / 256, 256, 0, stream>>>(ebuf, cursor, csr_src);
    k_agg1<<<N_NODES / 8, 256, 0, stream>>>(row_ptr, csr_src, x_h, agg1);
    k_gemm1<<<(N_NODES + 63) / 64, 256, 0, stream>>>(agg1, row_ptr, x, W1l, b1l, W1r,
                                                     gamma, beta, mean, var, h);
    k_gemm2<<<(N_NODES + 63) / 64, 256, 0, stream>>>(h, W2l, b2l, W2r, p2, out);
    k_agg2<<<N_NODES / 16, 256, 0, stream>>>(row_ptr, csr_src, p2, out);
}

// Round 4
// 528.805 us; speedup vs baseline: 1.2141x; 1.2141x over previous
//
#include <hip/hip_runtime.h>
#include <hip/hip_fp16.h>

#define N_NODES 100000
#define N_EDGES 1600000
#define SCAN_BLOCKS 196   // 196*512 = 100352 >= N_NODES

typedef _Float16 f16x8 __attribute__((ext_vector_type(8)));
typedef float    f32x4 __attribute__((ext_vector_type(4)));

// ---------------------------------------------------------------------------
// CSR build: histogram -> exclusive scan -> direct fill
// ---------------------------------------------------------------------------
__global__ __launch_bounds__(256) void k_hist(
    const int* __restrict__ ei, int* __restrict__ counts)
{
    int e = blockIdx.x * 256 + threadIdx.x;
    if (e < N_EDGES) atomicAdd(&counts[ei[N_EDGES + e]], 1);
}

__global__ __launch_bounds__(512) void k_scan1(
    const int* __restrict__ counts, int* __restrict__ row_ptr,
    int* __restrict__ blockSums)
{
    __shared__ int s[512];
    int t = threadIdx.x;
    int i = blockIdx.x * 512 + t;
    int c = (i < N_NODES) ? counts[i] : 0;
    s[t] = c;
    __syncthreads();
    #pragma unroll
    for (int off = 1; off < 512; off <<= 1) {
        int v = (t >= off) ? s[t - off] : 0;
        __syncthreads();
        s[t] += v;
        __syncthreads();
    }
    if (i < N_NODES) row_ptr[i] = s[t] - c;
    if (t == 511) blockSums[blockIdx.x] = s[511];
}

__global__ __launch_bounds__(256) void k_scan2(int* __restrict__ blockSums)
{
    __shared__ int s[256];
    int t = threadIdx.x;
    int c = (t < SCAN_BLOCKS) ? blockSums[t] : 0;
    s[t] = c;
    __syncthreads();
    #pragma unroll
    for (int off = 1; off < 256; off <<= 1) {
        int v = (t >= off) ? s[t - off] : 0;
        __syncthreads();
        s[t] += v;
        __syncthreads();
    }
    if (t < SCAN_BLOCKS) blockSums[t] = s[t] - c;
}

__global__ __launch_bounds__(512) void k_scan3(
    int* __restrict__ row_ptr, const int* __restrict__ blockSums,
    int* __restrict__ cursor)
{
    int i = blockIdx.x * 512 + threadIdx.x;
    if (i < N_NODES) {
        int v = row_ptr[i] + blockSums[blockIdx.x];
        row_ptr[i] = v;
        cursor[i]  = v;
    }
    if (i == 0) row_ptr[N_NODES] = N_EDGES;
}

__global__ __launch_bounds__(256) void k_fill(
    const int* __restrict__ ei, int* __restrict__ cursor,
    int* __restrict__ csr_src)
{
    int e = blockIdx.x * 256 + threadIdx.x;
    if (e < N_EDGES) {
        int dst = ei[N_EDGES + e];
        int pos = atomicAdd(&cursor[dst], 1);
        csr_src[pos] = ei[e];
    }
}

// ---------------------------------------------------------------------------
// dtype conversions
// ---------------------------------------------------------------------------
__global__ __launch_bounds__(256) void k_tohalf(
    const float* __restrict__ x, __half* __restrict__ x_h)
{
    int i = blockIdx.x * 256 + threadIdx.x;   // one float4 -> 4 halves
    if (i < N_NODES * 32) {
        float4 v = ((const float4*)x)[i];
        __half2 a = __floats2half2_rn(v.x, v.y);
        __half2 b = __floats2half2_rn(v.z, v.w);
        uint2 u = make_uint2(*(unsigned*)&a, *(unsigned*)&b);
        ((uint2*)x_h)[i] = u;
    }
}

__global__ __launch_bounds__(256) void k_wh(
    const float* __restrict__ W1l, const float* __restrict__ W1r,
    const float* __restrict__ W2l, const float* __restrict__ W2r,
    __half* __restrict__ W1l_h, __half* __restrict__ W1r_h,
    __half* __restrict__ W2l_h, __half* __restrict__ W2r_h)
{
    int t = blockIdx.x * 256 + threadIdx.x;
    if (t < 16384)      W1l_h[t] = __float2half(W1l[t]);
    else if (t < 32768) W1r_h[t - 16384] = __float2half(W1r[t - 16384]);
    else if (t < 40960) W2l_h[t - 32768] = __float2half(W2l[t - 32768]);
    else if (t < 49152) W2r_h[t - 40960] = __float2half(W2r[t - 40960]);
}

// ---------------------------------------------------------------------------
// K-agg1: agg_h[n] = sum_{e in row n} x_h[csr_src[e]]  (fp16 gather, fp32 acc,
// fp16 store).  32 lanes per node (8 B = 4 ch), 8 nodes per block, 4x unroll.
// ---------------------------------------------------------------------------
__device__ __forceinline__ void acc_row_h(
    const __half* __restrict__ x_h, int s, int lane, float4& acc)
{
    uint2 u = ((const uint2*)(x_h + (size_t)s * 128))[lane];
    __half2 a = *(__half2*)&u.x;
    __half2 b = *(__half2*)&u.y;
    float2 fa = __half22float2(a);
    float2 fb = __half22float2(b);
    acc.x += fa.x; acc.y += fa.y; acc.z += fb.x; acc.w += fb.y;
}

__global__ __launch_bounds__(256) void k_agg1(
    const int* __restrict__ row_ptr, const int* __restrict__ csr_src,
    const __half* __restrict__ x_h, __half* __restrict__ agg_h)
{
    int tid  = threadIdx.x;
    int n    = blockIdx.x * 8 + (tid >> 5);
    int lane = tid & 31;
    int e0 = row_ptr[n], e1 = row_ptr[n + 1];
    float4 acc = make_float4(0.f, 0.f, 0.f, 0.f);
    int e = e0;
    for (; e + 4 <= e1; e += 4) {
        int s0 = csr_src[e], s1 = csr_src[e + 1];
        int s2 = csr_src[e + 2], s3 = csr_src[e + 3];
        acc_row_h(x_h, s0, lane, acc);
        acc_row_h(x_h, s1, lane, acc);
        acc_row_h(x_h, s2, lane, acc);
        acc_row_h(x_h, s3, lane, acc);
    }
    for (; e < e1; ++e) acc_row_h(x_h, csr_src[e], lane, acc);
    __half2 h0 = __floats2half2_rn(acc.x, acc.y);
    __half2 h1 = __floats2half2_rn(acc.z, acc.w);
    uint2 u = make_uint2(*(unsigned*)&h0, *(unsigned*)&h1);
    ((uint2*)agg_h)[n * 32 + lane] = u;
}

// ---------------------------------------------------------------------------
// K-gemm1 (MFMA fp16): h = relu(bn( (aggsum@W1l^T)*invdeg + x@W1r^T + b1l ))
// Block: 64 nodes x 128 out-ch; 4 waves, wave w = rows [w*16,w*16+16).
// A staged fragment-major in LDS: A[kblock][node][8 halves].
// B frags loaded from global fp16 weights (L1/L2 resident).
// mfma_f32_16x16x32_f16: A[m=lane&15][k=q*8+j]; C: col=lane&15, row=q*4+reg.
// ---------------------------------------------------------------------------
__global__ __launch_bounds__(256) void k_gemm1(
    const __half* __restrict__ agg_h, const int* __restrict__ counts,
    const __half* __restrict__ x_h,
    const __half* __restrict__ W1l_h, const float* __restrict__ b1l,
    const __half* __restrict__ W1r_h,
    const float* __restrict__ gamma, const float* __restrict__ beta,
    const float* __restrict__ mean, const float* __restrict__ var,
    __half* __restrict__ h_h)
{
    __shared__ __half Aagg[16][64][8];   // 16 KB
    __shared__ __half Ax[16][64][8];     // 16 KB
    __shared__ __half Hs[64][136];       // 17.4 KB repack (136*2=272=17*16 B)
    int tid = threadIdx.x;
    int n0  = blockIdx.x * 64;
    // ---- stage A tiles (full K=128 both sides) ----
    {
        int n  = tid & 63;
        int kg = tid >> 6;               // kblocks 4kg..4kg+3 (each 8 halves)
        int ng = n0 + n;
        const uint4* pa = (const uint4*)(agg_h + (size_t)ng * 128 + kg * 32);
        const uint4* px = (const uint4*)(x_h   + (size_t)ng * 128 + kg * 32);
        #pragma unroll
        for (int i = 0; i < 4; ++i) {
            uint4 va = make_uint4(0, 0, 0, 0), vx = va;
            if (ng < N_NODES) { va = pa[i]; vx = px[i]; }
            *(uint4*)&Aagg[kg * 4 + i][n][0] = va;
            *(uint4*)&Ax[kg * 4 + i][n][0]   = vx;
        }
    }
    __syncthreads();
    int lane = tid & 63;
    int w = tid >> 6;
    int m = lane & 15;
    int q = lane >> 4;
    int row = w * 16 + m;
    f32x4 accL[8], accR[8];
    #pragma unroll
    for (int c = 0; c < 8; ++c) {
        accL[c] = (f32x4){0.f, 0.f, 0.f, 0.f};
        accR[c] = (f32x4){0.f, 0.f, 0.f, 0.f};
    }
    #pragma unroll
    for (int ks = 0; ks < 4; ++ks) {
        f16x8 aL = *(const f16x8*)&Aagg[ks * 4 + q][row][0];
        f16x8 aR = *(const f16x8*)&Ax[ks * 4 + q][row][0];
        #pragma unroll
        for (int ct = 0; ct < 8; ++ct) {
            f16x8 bL = *(const f16x8*)(W1l_h + (ct * 16 + m) * 128 + ks * 32 + q * 8);
            f16x8 bR = *(const f16x8*)(W1r_h + (ct * 16 + m) * 128 + ks * 32 + q * 8);
            accL[ct] = __builtin_amdgcn_mfma_f32_16x16x32_f16(aL, bL, accL[ct], 0, 0, 0);
            accR[ct] = __builtin_amdgcn_mfma_f32_16x16x32_f16(aR, bR, accR[ct], 0, 0, 0);
        }
    }
    // ---- epilogue: invdeg combine + BN + ReLU -> LDS fp16 -> coalesced out
    float invd[4];
    #pragma unroll
    for (int r = 0; r < 4; ++r) {
        int n = n0 + w * 16 + q * 4 + r;
        int d = (n < N_NODES) ? counts[n] : 1;
        invd[r] = 1.0f / fmaxf((float)d, 1.0f);
    }
    #pragma unroll
    for (int ct = 0; ct < 8; ++ct) {
        int col = ct * 16 + m;
        float s = gamma[col] * rsqrtf(var[col] + 1e-5f);
        float t = beta[col] + (b1l[col] - mean[col]) * s;
        #pragma unroll
        for (int r = 0; r < 4; ++r) {
            float v = accL[ct][r] * invd[r] + accR[ct][r];
            v = fmaxf(v * s + t, 0.f);
            Hs[w * 16 + q * 4 + r][col] = __float2half(v);
        }
    }
    __syncthreads();
    {
        int rr = tid & 63;
        int pg = tid >> 6;
        int ng = n0 + rr;
        if (ng < N_NODES) {
            uint4* dst = (uint4*)(h_h + (size_t)ng * 128);
            #pragma unroll
            for (int i = 0; i < 4; ++i)
                dst[pg * 4 + i] = *(const uint4*)&Hs[rr][(pg * 4 + i) * 8];
        }
    }
}

// ---------------------------------------------------------------------------
// K-gemm2 (MFMA fp16): stacked B = [W2l ; W2r] (N=128, K=128).
// C cols 0..63  -> p2 (fp16, for the layer-2 gather)
// C cols 64..127-> out (fp32, + b2l)
// ---------------------------------------------------------------------------
__global__ __launch_bounds__(256) void k_gemm2(
    const __half* __restrict__ h_h,
    const __half* __restrict__ W2l_h, const float* __restrict__ b2l,
    const __half* __restrict__ W2r_h,
    __half* __restrict__ p2, float* __restrict__ out)
{
    __shared__ __half Ah[16][64][8];   // 16 KB
    __shared__ float  Cs[64][132];     // 33.8 KB
    int tid = threadIdx.x;
    int n0  = blockIdx.x * 64;
    {
        int n  = tid & 63;
        int kg = tid >> 6;
        int ng = n0 + n;
        const uint4* ph = (const uint4*)(h_h + (size_t)ng * 128 + kg * 32);
        #pragma unroll
        for (int i = 0; i < 4; ++i) {
            uint4 vh = make_uint4(0, 0, 0, 0);
            if (ng < N_NODES) vh = ph[i];
            *(uint4*)&Ah[kg * 4 + i][n][0] = vh;
        }
    }
    __syncthreads();
    int lane = tid & 63;
    int w = tid >> 6;
    int m = lane & 15;
    int q = lane >> 4;
    int row = w * 16 + m;
    f32x4 acc[8];
    #pragma unroll
    for (int c = 0; c < 8; ++c) acc[c] = (f32x4){0.f, 0.f, 0.f, 0.f};
    #pragma unroll
    for (int ks = 0; ks < 4; ++ks) {
        f16x8 a = *(const f16x8*)&Ah[ks * 4 + q][row][0];
        #pragma unroll
        for (int ct = 0; ct < 8; ++ct) {
            const __half* W = (ct < 4)
                ? (W2l_h + (ct * 16 + m) * 128 + ks * 32 + q * 8)
                : (W2r_h + ((ct - 4) * 16 + m) * 128 + ks * 32 + q * 8);
            f16x8 b = *(const f16x8*)W;
            acc[ct] = __builtin_amdgcn_mfma_f32_16x16x32_f16(a, b, acc[ct], 0, 0, 0);
        }
    }
    #pragma unroll
    for (int ct = 0; ct < 8; ++ct) {
        int col = ct * 16 + m;
        #pragma unroll
        for (int r = 0; r < 4; ++r)
            Cs[w * 16 + q * 4 + r][col] = acc[ct][r];
    }
    __syncthreads();
    {
        int rr = tid & 63;
        int pg = tid >> 6;                 // 16-col group
        int ng = n0 + rr;
        if (ng < N_NODES) {
            // p2: cols 0..63 -> fp16
            union { __half hh[16]; uint4 u[2]; } tmp;
            #pragma unroll
            for (int c = 0; c < 16; ++c)
                tmp.hh[c] = __float2half(Cs[rr][pg * 16 + c]);
            uint4* dp = (uint4*)(p2 + (size_t)ng * 64 + pg * 16);
            dp[0] = tmp.u[0];
            dp[1] = tmp.u[1];
            // out: cols 64..127 -> fp32 + b2l
            #pragma unroll
            for (int i = 0; i < 4; ++i) {
                float4 v  = *(const float4*)&Cs[rr][64 + pg * 16 + i * 4];
                float4 bb = *(const float4*)(b2l + pg * 16 + i * 4);
                v.x += bb.x; v.y += bb.y; v.z += bb.z; v.w += bb.w;
                *(float4*)(out + (size_t)ng * 64 + pg * 16 + i * 4) = v;
            }
        }
    }
}

// ---------------------------------------------------------------------------
// K-agg2: out[n] += (sum_{e in row n} p2[csr_src[e]]) / max(deg,1)
// ---------------------------------------------------------------------------
__device__ __forceinline__ void acc_row_p2(
    const __half* __restrict__ p2, int s, int lane, float4& acc)
{
    uint2 u = ((const uint2*)(p2 + (size_t)s * 64))[lane];
    __half2 a = *(__half2*)&u.x;
    __half2 b = *(__half2*)&u.y;
    float2 fa = __half22float2(a);
    float2 fb = __half22float2(b);
    acc.x += fa.x; acc.y += fa.y; acc.z += fb.x; acc.w += fb.y;
}

__global__ __launch_bounds__(256) void k_agg2(
    const int* __restrict__ row_ptr, const int* __restrict__ csr_src,
    const __half* __restrict__ p2, float* __restrict__ out)
{
    int tid  = threadIdx.x;
    int n    = blockIdx.x * 16 + (tid >> 4);
    int lane = tid & 15;
    int e0 = row_ptr[n], e1 = row_ptr[n + 1];
    float4 acc = make_float4(0.f, 0.f, 0.f, 0.f);
    int e = e0;
    for (; e + 4 <= e1; e += 4) {
        int s0 = csr_src[e], s1 = csr_src[e + 1];
        int s2 = csr_src[e + 2], s3 = csr_src[e + 3];
        acc_row_p2(p2, s0, lane, acc);
        acc_row_p2(p2, s1, lane, acc);
        acc_row_p2(p2, s2, lane, acc);
        acc_row_p2(p2, s3, lane, acc);
    }
    for (; e < e1; ++e) acc_row_p2(p2, csr_src[e], lane, acc);
    float inv = 1.0f / fmaxf((float)(e1 - e0), 1.0f);
    float4* o = (float4*)out + n * 16 + lane;
    float4 cur = *o;
    cur.x += acc.x * inv; cur.y += acc.y * inv;
    cur.z += acc.z * inv; cur.w += acc.w * inv;
    *o = cur;
}

// ---------------------------------------------------------------------------
extern "C" void kernel_launch(void* const* d_in, const int* in_sizes, int n_in,
                              void* d_out, int out_size, void* d_ws, size_t ws_size,
                              hipStream_t stream)
{
    const float* x     = (const float*)d_in[0];
    const int*   ei    = (const int*)d_in[1];
    const float* W1l   = (const float*)d_in[2];
    const float* b1l   = (const float*)d_in[3];
    const float* W1r   = (const float*)d_in[4];
    const float* gamma = (const float*)d_in[5];
    const float* beta  = (const float*)d_in[6];
    const float* mean  = (const float*)d_in[7];
    const float* var   = (const float*)d_in[8];
    const float* W2l   = (const float*)d_in[9];
    const float* b2l   = (const float*)d_in[10];
    const float* W2r   = (const float*)d_in[11];
    float* out = (float*)d_out;

    char* ws = (char*)d_ws;
    __half* agg_h   = (__half*)(ws);                  // 25.6 MB (p2 aliases)
    __half* h_h     = (__half*)(ws + 25600000);       // 25.6 MB
    __half* x_h     = (__half*)(ws + 51200000);       // 25.6 MB
    int*    csr_src = (int*)(ws + 76800000);          // 6.4 MB
    int*    row_ptr = (int*)(ws + 83200000);          // 400 KB + 16
    int*    counts  = (int*)(ws + 83600016);          // 400 KB
    int*    cursor  = (int*)(ws + 84000016);          // 400 KB
    int*    blockSums = (int*)(ws + 84400016);        // 1 KB
    __half* W1l_h   = (__half*)(ws + 84401040);       // 32 KB
    __half* W1r_h   = (__half*)(ws + 84433808);       // 32 KB
    __half* W2l_h   = (__half*)(ws + 84466576);       // 16 KB
    __half* W2r_h   = (__half*)(ws + 84482960);       // 16 KB
    __half* p2      = agg_h;                          // agg_h dead after gemm1

    hipMemsetAsync(counts, 0, N_NODES * sizeof(int), stream);
    k_hist<<<(N_EDGES + 255) / 256, 256, 0, stream>>>(ei, counts);
    k_tohalf<<<(N_NODES * 32 + 255) / 256, 256, 0, stream>>>(x, x_h);
    k_wh<<<192, 256, 0, stream>>>(W1l, W1r, W2l, W2r, W1l_h, W1r_h, W2l_h, W2r_h);
    k_scan1<<<SCAN_BLOCKS, 512, 0, stream>>>(counts, row_ptr, blockSums);
    k_scan2<<<1, 256, 0, stream>>>(blockSums);
    k_scan3<<<SCAN_BLOCKS, 512, 0, stream>>>(row_ptr, blockSums, cursor);
    k_fill<<<(N_EDGES + 255) / 256, 256, 0, stream>>>(ei, cursor, csr_src);
    k_agg1<<<N_NODES / 8, 256, 0, stream>>>(row_ptr, csr_src, x_h, agg_h);
    k_gemm1<<<(N_NODES + 63) / 64, 256, 0, stream>>>(agg_h, counts, x_h,
                                                     W1l_h, b1l, W1r_h,
                                                     gamma, beta, mean, var, h_h);
    k_gemm2<<<(N_NODES + 63) / 64, 256, 0, stream>>>(h_h, W2l_h, b2l, W2r_h,
                                                     p2, out);
    k_agg2<<<N_NODES / 16, 256, 0, stream>>>(row_ptr, csr_src, p2, out);
}

// Round 5
// 486.793 us; speedup vs baseline: 1.3188x; 1.0863x over previous
//
#include <hip/hip_runtime.h>
#include <hip/hip_fp16.h>

#define N_NODES 100000
#define N_EDGES 1600000
#define SCAN_BLOCKS 196   // 196*512 = 100352 >= N_NODES
#define TILE 2048
#define NBUK 64
#define BSH 11            // bucket = dst >> 11 (2048 nodes/bucket, 49 used)

typedef _Float16 f16x8 __attribute__((ext_vector_type(8)));
typedef float    f32x4 __attribute__((ext_vector_type(4)));

// ---------------------------------------------------------------------------
// CSR build: histogram -> exclusive scan -> LDS-staged bin -> fine fill
// ---------------------------------------------------------------------------
__global__ __launch_bounds__(256) void k_hist(
    const int* __restrict__ ei, int* __restrict__ counts)
{
    int e = blockIdx.x * 256 + threadIdx.x;
    if (e < N_EDGES) atomicAdd(&counts[ei[N_EDGES + e]], 1);
}

__global__ __launch_bounds__(512) void k_scan1(
    const int* __restrict__ counts, int* __restrict__ row_ptr,
    int* __restrict__ blockSums)
{
    __shared__ int s[512];
    int t = threadIdx.x;
    int i = blockIdx.x * 512 + t;
    int c = (i < N_NODES) ? counts[i] : 0;
    s[t] = c;
    __syncthreads();
    #pragma unroll
    for (int off = 1; off < 512; off <<= 1) {
        int v = (t >= off) ? s[t - off] : 0;
        __syncthreads();
        s[t] += v;
        __syncthreads();
    }
    if (i < N_NODES) row_ptr[i] = s[t] - c;
    if (t == 511) blockSums[blockIdx.x] = s[511];
}

__global__ __launch_bounds__(256) void k_scan2(int* __restrict__ blockSums)
{
    __shared__ int s[256];
    int t = threadIdx.x;
    int c = (t < SCAN_BLOCKS) ? blockSums[t] : 0;
    s[t] = c;
    __syncthreads();
    #pragma unroll
    for (int off = 1; off < 256; off <<= 1) {
        int v = (t >= off) ? s[t - off] : 0;
        __syncthreads();
        s[t] += v;
        __syncthreads();
    }
    if (t < SCAN_BLOCKS) blockSums[t] = s[t] - c;
}

__global__ __launch_bounds__(512) void k_scan3(
    int* __restrict__ row_ptr, const int* __restrict__ blockSums,
    int* __restrict__ cursor)
{
    int i = blockIdx.x * 512 + threadIdx.x;
    if (i < N_NODES) {
        int v = row_ptr[i] + blockSums[blockIdx.x];
        row_ptr[i] = v;
        cursor[i]  = v;
    }
    if (i == 0) row_ptr[N_NODES] = N_EDGES;
}

// bucket b's ebuf region starts at row_ptr[b*2048] (sum of node counts below)
__global__ __launch_bounds__(64) void k_bcur(
    const int* __restrict__ row_ptr, int* __restrict__ bcur)
{
    int b = threadIdx.x;
    if (b < NBUK) bcur[b] = row_ptr[min(b << BSH, N_NODES)];
}

// Pass A: LDS-staged bucket partition. Tile = 2048 edges; bucket-sort the
// tile in LDS, then copy out in LDS-sequential order -> coalesced runs
// (avg 32 entries = 256 B per bucket per tile).
__global__ __launch_bounds__(256) void k_binA(
    const int* __restrict__ ei, int* __restrict__ bcur,
    int2* __restrict__ ebuf)
{
    __shared__ int2 scratch[TILE];   // 16 KB
    __shared__ int hist[NBUK];
    __shared__ int tstart[NBUK];
    __shared__ int gbase[NBUK];
    int t = threadIdx.x;
    int e0 = blockIdx.x * TILE;
    int tile_n = min(TILE, N_EDGES - e0);
    if (t < NBUK) hist[t] = 0;
    __syncthreads();
    int srcs[8], dsts[8], rank[8], bks[8];
    #pragma unroll
    for (int i = 0; i < 8; ++i) {
        int e = e0 + i * 256 + t;
        bks[i] = -1;
        if (e < N_EDGES) {
            srcs[i] = ei[e];
            dsts[i] = ei[N_EDGES + e];
            bks[i]  = dsts[i] >> BSH;
            rank[i] = atomicAdd(&hist[bks[i]], 1);
        }
    }
    __syncthreads();
    if (t == 0) {
        int s = 0;
        #pragma unroll
        for (int b = 0; b < NBUK; ++b) { tstart[b] = s; s += hist[b]; }
    }
    __syncthreads();
    if (t < NBUK && hist[t] > 0)
        gbase[t] = atomicAdd(&bcur[t], hist[t]);
    __syncthreads();
    #pragma unroll
    for (int i = 0; i < 8; ++i)
        if (bks[i] >= 0)
            scratch[tstart[bks[i]] + rank[i]] = make_int2(srcs[i], dsts[i]);
    __syncthreads();
    for (int p = t; p < tile_n; p += 256) {
        int2 sd = scratch[p];
        int b = sd.y >> BSH;
        ebuf[gbase[b] + (p - tstart[b])] = sd;
    }
}

// Pass B: fine fill; ebuf is bucket-ordered so the active csr_src write
// window per bucket (~130 KB) stays L2-resident.
__global__ __launch_bounds__(256) void k_fillB(
    const int2* __restrict__ ebuf, int* __restrict__ cursor,
    int* __restrict__ csr_src)
{
    int i = blockIdx.x * 256 + threadIdx.x;
    if (i < N_EDGES) {
        int2 sd = ebuf[i];
        int pos = atomicAdd(&cursor[sd.y], 1);
        csr_src[pos] = sd.x;
    }
}

// ---------------------------------------------------------------------------
// dtype conversions
// ---------------------------------------------------------------------------
__global__ __launch_bounds__(256) void k_tohalf(
    const float* __restrict__ x, __half* __restrict__ x_h)
{
    int i = blockIdx.x * 256 + threadIdx.x;
    if (i < N_NODES * 32) {
        float4 v = ((const float4*)x)[i];
        __half2 a = __floats2half2_rn(v.x, v.y);
        __half2 b = __floats2half2_rn(v.z, v.w);
        uint2 u = make_uint2(*(unsigned*)&a, *(unsigned*)&b);
        ((uint2*)x_h)[i] = u;
    }
}

__global__ __launch_bounds__(256) void k_wh(
    const float* __restrict__ W1l, const float* __restrict__ W1r,
    const float* __restrict__ W2l, const float* __restrict__ W2r,
    __half* __restrict__ W1l_h, __half* __restrict__ W1r_h,
    __half* __restrict__ W2l_h, __half* __restrict__ W2r_h)
{
    int t = blockIdx.x * 256 + threadIdx.x;
    if (t < 16384)      W1l_h[t] = __float2half(W1l[t]);
    else if (t < 32768) W1r_h[t - 16384] = __float2half(W1r[t - 16384]);
    else if (t < 40960) W2l_h[t - 32768] = __float2half(W2l[t - 32768]);
    else if (t < 49152) W2r_h[t - 40960] = __float2half(W2r[t - 40960]);
}

// ---------------------------------------------------------------------------
// K-agg1: agg_h[n] = sum_{e in row n} x_h[csr_src[e]]
// ---------------------------------------------------------------------------
__device__ __forceinline__ void acc_row_h(
    const __half* __restrict__ x_h, int s, int lane, float4& acc)
{
    uint2 u = ((const uint2*)(x_h + (size_t)s * 128))[lane];
    __half2 a = *(__half2*)&u.x;
    __half2 b = *(__half2*)&u.y;
    float2 fa = __half22float2(a);
    float2 fb = __half22float2(b);
    acc.x += fa.x; acc.y += fa.y; acc.z += fb.x; acc.w += fb.y;
}

__global__ __launch_bounds__(256) void k_agg1(
    const int* __restrict__ row_ptr, const int* __restrict__ csr_src,
    const __half* __restrict__ x_h, __half* __restrict__ agg_h)
{
    int tid  = threadIdx.x;
    int n    = blockIdx.x * 8 + (tid >> 5);
    int lane = tid & 31;
    int e0 = row_ptr[n], e1 = row_ptr[n + 1];
    float4 acc = make_float4(0.f, 0.f, 0.f, 0.f);
    int e = e0;
    for (; e + 4 <= e1; e += 4) {
        int s0 = csr_src[e], s1 = csr_src[e + 1];
        int s2 = csr_src[e + 2], s3 = csr_src[e + 3];
        acc_row_h(x_h, s0, lane, acc);
        acc_row_h(x_h, s1, lane, acc);
        acc_row_h(x_h, s2, lane, acc);
        acc_row_h(x_h, s3, lane, acc);
    }
    for (; e < e1; ++e) acc_row_h(x_h, csr_src[e], lane, acc);
    __half2 h0 = __floats2half2_rn(acc.x, acc.y);
    __half2 h1 = __floats2half2_rn(acc.z, acc.w);
    uint2 u = make_uint2(*(unsigned*)&h0, *(unsigned*)&h1);
    ((uint2*)agg_h)[n * 32 + lane] = u;
}

// ---------------------------------------------------------------------------
// K-gemm1 (MFMA fp16): h = relu(bn( (aggsum@W1l^T)*invdeg + x@W1r^T + b1l ))
// ---------------------------------------------------------------------------
__global__ __launch_bounds__(256) void k_gemm1(
    const __half* __restrict__ agg_h, const int* __restrict__ counts,
    const __half* __restrict__ x_h,
    const __half* __restrict__ W1l_h, const float* __restrict__ b1l,
    const __half* __restrict__ W1r_h,
    const float* __restrict__ gamma, const float* __restrict__ beta,
    const float* __restrict__ mean, const float* __restrict__ var,
    __half* __restrict__ h_h)
{
    __shared__ __half Aagg[16][64][8];
    __shared__ __half Ax[16][64][8];
    __shared__ __half Hs[64][136];
    int tid = threadIdx.x;
    int n0  = blockIdx.x * 64;
    {
        int n  = tid & 63;
        int kg = tid >> 6;
        int ng = n0 + n;
        const uint4* pa = (const uint4*)(agg_h + (size_t)ng * 128 + kg * 32);
        const uint4* px = (const uint4*)(x_h   + (size_t)ng * 128 + kg * 32);
        #pragma unroll
        for (int i = 0; i < 4; ++i) {
            uint4 va = make_uint4(0, 0, 0, 0), vx = va;
            if (ng < N_NODES) { va = pa[i]; vx = px[i]; }
            *(uint4*)&Aagg[kg * 4 + i][n][0] = va;
            *(uint4*)&Ax[kg * 4 + i][n][0]   = vx;
        }
    }
    __syncthreads();
    int lane = tid & 63;
    int w = tid >> 6;
    int m = lane & 15;
    int q = lane >> 4;
    int row = w * 16 + m;
    f32x4 accL[8], accR[8];
    #pragma unroll
    for (int c = 0; c < 8; ++c) {
        accL[c] = (f32x4){0.f, 0.f, 0.f, 0.f};
        accR[c] = (f32x4){0.f, 0.f, 0.f, 0.f};
    }
    #pragma unroll
    for (int ks = 0; ks < 4; ++ks) {
        f16x8 aL = *(const f16x8*)&Aagg[ks * 4 + q][row][0];
        f16x8 aR = *(const f16x8*)&Ax[ks * 4 + q][row][0];
        #pragma unroll
        for (int ct = 0; ct < 8; ++ct) {
            f16x8 bL = *(const f16x8*)(W1l_h + (ct * 16 + m) * 128 + ks * 32 + q * 8);
            f16x8 bR = *(const f16x8*)(W1r_h + (ct * 16 + m) * 128 + ks * 32 + q * 8);
            accL[ct] = __builtin_amdgcn_mfma_f32_16x16x32_f16(aL, bL, accL[ct], 0, 0, 0);
            accR[ct] = __builtin_amdgcn_mfma_f32_16x16x32_f16(aR, bR, accR[ct], 0, 0, 0);
        }
    }
    float invd[4];
    #pragma unroll
    for (int r = 0; r < 4; ++r) {
        int n = n0 + w * 16 + q * 4 + r;
        int d = (n < N_NODES) ? counts[n] : 1;
        invd[r] = 1.0f / fmaxf((float)d, 1.0f);
    }
    #pragma unroll
    for (int ct = 0; ct < 8; ++ct) {
        int col = ct * 16 + m;
        float s = gamma[col] * rsqrtf(var[col] + 1e-5f);
        float t = beta[col] + (b1l[col] - mean[col]) * s;
        #pragma unroll
        for (int r = 0; r < 4; ++r) {
            float v = accL[ct][r] * invd[r] + accR[ct][r];
            v = fmaxf(v * s + t, 0.f);
            Hs[w * 16 + q * 4 + r][col] = __float2half(v);
        }
    }
    __syncthreads();
    {
        int rr = tid & 63;
        int pg = tid >> 6;
        int ng = n0 + rr;
        if (ng < N_NODES) {
            uint4* dst = (uint4*)(h_h + (size_t)ng * 128);
            #pragma unroll
            for (int i = 0; i < 4; ++i)
                dst[pg * 4 + i] = *(const uint4*)&Hs[rr][(pg * 4 + i) * 8];
        }
    }
}

// ---------------------------------------------------------------------------
// K-gemm2 (MFMA fp16): stacked B = [W2l ; W2r]
// ---------------------------------------------------------------------------
__global__ __launch_bounds__(256) void k_gemm2(
    const __half* __restrict__ h_h,
    const __half* __restrict__ W2l_h, const float* __restrict__ b2l,
    const __half* __restrict__ W2r_h,
    __half* __restrict__ p2, float* __restrict__ out)
{
    __shared__ __half Ah[16][64][8];
    __shared__ float  Cs[64][132];
    int tid = threadIdx.x;
    int n0  = blockIdx.x * 64;
    {
        int n  = tid & 63;
        int kg = tid >> 6;
        int ng = n0 + n;
        const uint4* ph = (const uint4*)(h_h + (size_t)ng * 128 + kg * 32);
        #pragma unroll
        for (int i = 0; i < 4; ++i) {
            uint4 vh = make_uint4(0, 0, 0, 0);
            if (ng < N_NODES) vh = ph[i];
            *(uint4*)&Ah[kg * 4 + i][n][0] = vh;
        }
    }
    __syncthreads();
    int lane = tid & 63;
    int w = tid >> 6;
    int m = lane & 15;
    int q = lane >> 4;
    int row = w * 16 + m;
    f32x4 acc[8];
    #pragma unroll
    for (int c = 0; c < 8; ++c) acc[c] = (f32x4){0.f, 0.f, 0.f, 0.f};
    #pragma unroll
    for (int ks = 0; ks < 4; ++ks) {
        f16x8 a = *(const f16x8*)&Ah[ks * 4 + q][row][0];
        #pragma unroll
        for (int ct = 0; ct < 8; ++ct) {
            const __half* W = (ct < 4)
                ? (W2l_h + (ct * 16 + m) * 128 + ks * 32 + q * 8)
                : (W2r_h + ((ct - 4) * 16 + m) * 128 + ks * 32 + q * 8);
            f16x8 b = *(const f16x8*)W;
            acc[ct] = __builtin_amdgcn_mfma_f32_16x16x32_f16(a, b, acc[ct], 0, 0, 0);
        }
    }
    #pragma unroll
    for (int ct = 0; ct < 8; ++ct) {
        int col = ct * 16 + m;
        #pragma unroll
        for (int r = 0; r < 4; ++r)
            Cs[w * 16 + q * 4 + r][col] = acc[ct][r];
    }
    __syncthreads();
    {
        int rr = tid & 63;
        int pg = tid >> 6;
        int ng = n0 + rr;
        if (ng < N_NODES) {
            union { __half hh[16]; uint4 u[2]; } tmp;
            #pragma unroll
            for (int c = 0; c < 16; ++c)
                tmp.hh[c] = __float2half(Cs[rr][pg * 16 + c]);
            uint4* dp = (uint4*)(p2 + (size_t)ng * 64 + pg * 16);
            dp[0] = tmp.u[0];
            dp[1] = tmp.u[1];
            #pragma unroll
            for (int i = 0; i < 4; ++i) {
                float4 v  = *(const float4*)&Cs[rr][64 + pg * 16 + i * 4];
                float4 bb = *(const float4*)(b2l + pg * 16 + i * 4);
                v.x += bb.x; v.y += bb.y; v.z += bb.z; v.w += bb.w;
                *(float4*)(out + (size_t)ng * 64 + pg * 16 + i * 4) = v;
            }
        }
    }
}

// ---------------------------------------------------------------------------
// K-agg2: out[n] += (sum_{e in row n} p2[csr_src[e]]) / max(deg,1)
// ---------------------------------------------------------------------------
__device__ __forceinline__ void acc_row_p2(
    const __half* __restrict__ p2, int s, int lane, float4& acc)
{
    uint2 u = ((const uint2*)(p2 + (size_t)s * 64))[lane];
    __half2 a = *(__half2*)&u.x;
    __half2 b = *(__half2*)&u.y;
    float2 fa = __half22float2(a);
    float2 fb = __half22float2(b);
    acc.x += fa.x; acc.y += fa.y; acc.z += fb.x; acc.w += fb.y;
}

__global__ __launch_bounds__(256) void k_agg2(
    const int* __restrict__ row_ptr, const int* __restrict__ csr_src,
    const __half* __restrict__ p2, float* __restrict__ out)
{
    int tid  = threadIdx.x;
    int n    = blockIdx.x * 16 + (tid >> 4);
    int lane = tid & 15;
    int e0 = row_ptr[n], e1 = row_ptr[n + 1];
    float4 acc = make_float4(0.f, 0.f, 0.f, 0.f);
    int e = e0;
    for (; e + 4 <= e1; e += 4) {
        int s0 = csr_src[e], s1 = csr_src[e + 1];
        int s2 = csr_src[e + 2], s3 = csr_src[e + 3];
        acc_row_p2(p2, s0, lane, acc);
        acc_row_p2(p2, s1, lane, acc);
        acc_row_p2(p2, s2, lane, acc);
        acc_row_p2(p2, s3, lane, acc);
    }
    for (; e < e1; ++e) acc_row_p2(p2, csr_src[e], lane, acc);
    float inv = 1.0f / fmaxf((float)(e1 - e0), 1.0f);
    float4* o = (float4*)out + n * 16 + lane;
    float4 cur = *o;
    cur.x += acc.x * inv; cur.y += acc.y * inv;
    cur.z += acc.z * inv; cur.w += acc.w * inv;
    *o = cur;
}

// ---------------------------------------------------------------------------
extern "C" void kernel_launch(void* const* d_in, const int* in_sizes, int n_in,
                              void* d_out, int out_size, void* d_ws, size_t ws_size,
                              hipStream_t stream)
{
    const float* x     = (const float*)d_in[0];
    const int*   ei    = (const int*)d_in[1];
    const float* W1l   = (const float*)d_in[2];
    const float* b1l   = (const float*)d_in[3];
    const float* W1r   = (const float*)d_in[4];
    const float* gamma = (const float*)d_in[5];
    const float* beta  = (const float*)d_in[6];
    const float* mean  = (const float*)d_in[7];
    const float* var   = (const float*)d_in[8];
    const float* W2l   = (const float*)d_in[9];
    const float* b2l   = (const float*)d_in[10];
    const float* W2r   = (const float*)d_in[11];
    float* out = (float*)d_out;

    char* ws = (char*)d_ws;
    __half* agg_h   = (__half*)(ws);                  // 25.6 MB (p2 aliases)
    __half* h_h     = (__half*)(ws + 25600000);       // 25.6 MB
    __half* x_h     = (__half*)(ws + 51200000);       // 25.6 MB
    int*    csr_src = (int*)(ws + 76800000);          // 6.4 MB
    int*    row_ptr = (int*)(ws + 83200000);          // 400 KB + 16
    int*    counts  = (int*)(ws + 83600016);          // 400 KB
    int*    cursor  = (int*)(ws + 84000016);          // 400 KB
    int*    blockSums = (int*)(ws + 84400016);        // 1 KB
    __half* W1l_h   = (__half*)(ws + 84401040);       // 32 KB
    __half* W1r_h   = (__half*)(ws + 84433808);       // 32 KB
    __half* W2l_h   = (__half*)(ws + 84466576);       // 16 KB
    __half* W2r_h   = (__half*)(ws + 84482960);       // 16 KB
    int2*   ebuf    = (int2*)(ws + 84499344);         // 12.8 MB
    int*    bcur    = (int*)(ws + 97299344);          // 256 B
    __half* p2      = agg_h;

    hipMemsetAsync(counts, 0, N_NODES * sizeof(int), stream);
    k_hist<<<(N_EDGES + 255) / 256, 256, 0, stream>>>(ei, counts);
    k_tohalf<<<(N_NODES * 32 + 255) / 256, 256, 0, stream>>>(x, x_h);
    k_wh<<<192, 256, 0, stream>>>(W1l, W1r, W2l, W2r, W1l_h, W1r_h, W2l_h, W2r_h);
    k_scan1<<<SCAN_BLOCKS, 512, 0, stream>>>(counts, row_ptr, blockSums);
    k_scan2<<<1, 256, 0, stream>>>(blockSums);
    k_scan3<<<SCAN_BLOCKS, 512, 0, stream>>>(row_ptr, blockSums, cursor);
    k_bcur<<<1, 64, 0, stream>>>(row_ptr, bcur);
    k_binA<<<(N_EDGES + TILE - 1) / TILE, 256, 0, stream>>>(ei, bcur, ebuf);
    k_fillB<<<(N_EDGES + 255) / 256, 256, 0, stream>>>(ebuf, cursor, csr_src);
    k_agg1<<<N_NODES / 8, 256, 0, stream>>>(row_ptr, csr_src, x_h, agg_h);
    k_gemm1<<<(N_NODES + 63) / 64, 256, 0, stream>>>(agg_h, counts, x_h,
                                                     W1l_h, b1l, W1r_h,
                                                     gamma, beta, mean, var, h_h);
    k_gemm2<<<(N_NODES + 63) / 64, 256, 0, stream>>>(h_h, W2l_h, b2l, W2r_h,
                                                     p2, out);
    k_agg2<<<N_NODES / 16, 256, 0, stream>>>(row_ptr, csr_src, p2, out);
}

// Round 6
// 435.796 us; speedup vs baseline: 1.4732x; 1.1170x over previous
//
#include <hip/hip_runtime.h>
#include <hip/hip_fp16.h>

#define N_NODES 100000
#define N_EDGES 1600000
#define SCAN_BLOCKS 196   // 196*512 = 100352 >= N_NODES
#define TILE 2048
#define NBUK 64
#define BSH 11            // bucket = dst >> 11 (2048 nodes/bucket, 49 used)

typedef _Float16 f16x8 __attribute__((ext_vector_type(8)));
typedef float    f32x4 __attribute__((ext_vector_type(4)));

// ---------------------------------------------------------------------------
// CSR build: histogram -> exclusive scan -> LDS-staged bin -> fine fill
// ---------------------------------------------------------------------------
__global__ __launch_bounds__(256) void k_hist(
    const int* __restrict__ ei, int* __restrict__ counts)
{
    int e = blockIdx.x * 256 + threadIdx.x;
    if (e < N_EDGES) atomicAdd(&counts[ei[N_EDGES + e]], 1);
}

__global__ __launch_bounds__(512) void k_scan1(
    const int* __restrict__ counts, int* __restrict__ row_ptr,
    int* __restrict__ blockSums)
{
    __shared__ int s[512];
    int t = threadIdx.x;
    int i = blockIdx.x * 512 + t;
    int c = (i < N_NODES) ? counts[i] : 0;
    s[t] = c;
    __syncthreads();
    #pragma unroll
    for (int off = 1; off < 512; off <<= 1) {
        int v = (t >= off) ? s[t - off] : 0;
        __syncthreads();
        s[t] += v;
        __syncthreads();
    }
    if (i < N_NODES) row_ptr[i] = s[t] - c;
    if (t == 511) blockSums[blockIdx.x] = s[511];
}

__global__ __launch_bounds__(256) void k_scan2(int* __restrict__ blockSums)
{
    __shared__ int s[256];
    int t = threadIdx.x;
    int c = (t < SCAN_BLOCKS) ? blockSums[t] : 0;
    s[t] = c;
    __syncthreads();
    #pragma unroll
    for (int off = 1; off < 256; off <<= 1) {
        int v = (t >= off) ? s[t - off] : 0;
        __syncthreads();
        s[t] += v;
        __syncthreads();
    }
    if (t < SCAN_BLOCKS) blockSums[t] = s[t] - c;
}

__global__ __launch_bounds__(512) void k_scan3(
    int* __restrict__ row_ptr, const int* __restrict__ blockSums,
    int* __restrict__ cursor)
{
    int i = blockIdx.x * 512 + threadIdx.x;
    if (i < N_NODES) {
        int v = row_ptr[i] + blockSums[blockIdx.x];
        row_ptr[i] = v;
        cursor[i]  = v;
    }
    if (i == 0) row_ptr[N_NODES] = N_EDGES;
}

__global__ __launch_bounds__(64) void k_bcur(
    const int* __restrict__ row_ptr, int* __restrict__ bcur)
{
    int b = threadIdx.x;
    if (b < NBUK) bcur[b] = row_ptr[min(b << BSH, N_NODES)];
}

// Pass A: LDS-staged bucket partition (wavefront-coalesced writes)
__global__ __launch_bounds__(256) void k_binA(
    const int* __restrict__ ei, int* __restrict__ bcur,
    int2* __restrict__ ebuf)
{
    __shared__ int2 scratch[TILE];   // 16 KB
    __shared__ int hist[NBUK];
    __shared__ int tstart[NBUK];
    __shared__ int gbase[NBUK];
    int t = threadIdx.x;
    int e0 = blockIdx.x * TILE;
    int tile_n = min(TILE, N_EDGES - e0);
    if (t < NBUK) hist[t] = 0;
    __syncthreads();
    int srcs[8], dsts[8], rank[8], bks[8];
    #pragma unroll
    for (int i = 0; i < 8; ++i) {
        int e = e0 + i * 256 + t;
        bks[i] = -1;
        if (e < N_EDGES) {
            srcs[i] = ei[e];
            dsts[i] = ei[N_EDGES + e];
            bks[i]  = dsts[i] >> BSH;
            rank[i] = atomicAdd(&hist[bks[i]], 1);
        }
    }
    __syncthreads();
    if (t == 0) {
        int s = 0;
        #pragma unroll
        for (int b = 0; b < NBUK; ++b) { tstart[b] = s; s += hist[b]; }
    }
    __syncthreads();
    if (t < NBUK && hist[t] > 0)
        gbase[t] = atomicAdd(&bcur[t], hist[t]);
    __syncthreads();
    #pragma unroll
    for (int i = 0; i < 8; ++i)
        if (bks[i] >= 0)
            scratch[tstart[bks[i]] + rank[i]] = make_int2(srcs[i], dsts[i]);
    __syncthreads();
    for (int p = t; p < tile_n; p += 256) {
        int2 sd = scratch[p];
        int b = sd.y >> BSH;
        ebuf[gbase[b] + (p - tstart[b])] = sd;
    }
}

// Pass B: fine fill over bucket-ordered edges (L2-resident write windows)
__global__ __launch_bounds__(256) void k_fillB(
    const int2* __restrict__ ebuf, int* __restrict__ cursor,
    int* __restrict__ csr_src)
{
    int i = blockIdx.x * 256 + threadIdx.x;
    if (i < N_EDGES) {
        int2 sd = ebuf[i];
        int pos = atomicAdd(&cursor[sd.y], 1);
        csr_src[pos] = sd.x;
    }
}

// ---------------------------------------------------------------------------
// dtype conversions
// ---------------------------------------------------------------------------
__global__ __launch_bounds__(256) void k_tohalf(
    const float* __restrict__ x, __half* __restrict__ x_h)
{
    int i = blockIdx.x * 256 + threadIdx.x;
    if (i < N_NODES * 32) {
        float4 v = ((const float4*)x)[i];
        __half2 a = __floats2half2_rn(v.x, v.y);
        __half2 b = __floats2half2_rn(v.z, v.w);
        uint2 u = make_uint2(*(unsigned*)&a, *(unsigned*)&b);
        ((uint2*)x_h)[i] = u;
    }
}

// Fragment-ordered fp16 weights: Wf[((ct*4+ks)*64+lane)*8+j] =
// W[(ct*16 + (lane&15))*128 + ks*32 + (lane>>4)*8 + j]
// -> MFMA B-loads become base + lane*8 + const, coalesced & independent.
__global__ __launch_bounds__(256) void k_wfrag(
    const float* __restrict__ W1l, const float* __restrict__ W1r,
    const float* __restrict__ W2l, const float* __restrict__ W2r,
    __half* __restrict__ W1lf, __half* __restrict__ W1rf,
    __half* __restrict__ W2f)
{
    int t = blockIdx.x * 256 + threadIdx.x;
    if (t >= 49152) return;
    int tt = t & 16383;
    int j    = tt & 7;
    int lane = (tt >> 3) & 63;
    int ks   = (tt >> 9) & 3;
    int ct   = tt >> 11;
    int m = lane & 15, q = lane >> 4;
    int row = ct * 16 + m;
    int col = ks * 32 + q * 8 + j;
    if (t < 16384) {
        W1lf[tt] = __float2half(W1l[row * 128 + col]);
    } else if (t < 32768) {
        W1rf[tt] = __float2half(W1r[row * 128 + col]);
    } else {
        // stacked [W2l ; W2r]: ct<4 -> W2l row ct*16+m; ct>=4 -> W2r
        float v = (ct < 4) ? W2l[row * 128 + col]
                           : W2r[(row - 64) * 128 + col];
        W2f[tt] = __float2half(v);
    }
}

// ---------------------------------------------------------------------------
// K-agg1: agg_h[n] = sum_{e in row n} x_h[csr_src[e]]
// ---------------------------------------------------------------------------
__device__ __forceinline__ void acc_row_h(
    const __half* __restrict__ x_h, int s, int lane, float4& acc)
{
    uint2 u = ((const uint2*)(x_h + (size_t)s * 128))[lane];
    __half2 a = *(__half2*)&u.x;
    __half2 b = *(__half2*)&u.y;
    float2 fa = __half22float2(a);
    float2 fb = __half22float2(b);
    acc.x += fa.x; acc.y += fa.y; acc.z += fb.x; acc.w += fb.y;
}

__global__ __launch_bounds__(256) void k_agg1(
    const int* __restrict__ row_ptr, const int* __restrict__ csr_src,
    const __half* __restrict__ x_h, __half* __restrict__ agg_h)
{
    int tid  = threadIdx.x;
    int n    = blockIdx.x * 8 + (tid >> 5);
    int lane = tid & 31;
    int e0 = row_ptr[n], e1 = row_ptr[n + 1];
    float4 acc = make_float4(0.f, 0.f, 0.f, 0.f);
    int e = e0;
    for (; e + 4 <= e1; e += 4) {
        int s0 = csr_src[e], s1 = csr_src[e + 1];
        int s2 = csr_src[e + 2], s3 = csr_src[e + 3];
        acc_row_h(x_h, s0, lane, acc);
        acc_row_h(x_h, s1, lane, acc);
        acc_row_h(x_h, s2, lane, acc);
        acc_row_h(x_h, s3, lane, acc);
    }
    for (; e < e1; ++e) acc_row_h(x_h, csr_src[e], lane, acc);
    __half2 h0 = __floats2half2_rn(acc.x, acc.y);
    __half2 h1 = __floats2half2_rn(acc.z, acc.w);
    uint2 u = make_uint2(*(unsigned*)&h0, *(unsigned*)&h1);
    ((uint2*)agg_h)[n * 32 + lane] = u;
}

// ---------------------------------------------------------------------------
// K-gemm1 (MFMA fp16): h = relu(bn( (aggsum@W1l^T)*invdeg + x@W1r^T + b1l ))
// B from fragment-ordered global buffers (coalesced, compiler-pipelined).
// LDS: A-staging (32 KB) aliased with epilogue repack Hs (17.4 KB).
// ---------------------------------------------------------------------------
__global__ __launch_bounds__(256) void k_gemm1(
    const __half* __restrict__ agg_h, const int* __restrict__ counts,
    const __half* __restrict__ x_h,
    const __half* __restrict__ W1lf, const float* __restrict__ b1l,
    const __half* __restrict__ W1rf,
    const float* __restrict__ gamma, const float* __restrict__ beta,
    const float* __restrict__ mean, const float* __restrict__ var,
    __half* __restrict__ h_h)
{
    __shared__ char sm[32768];
    __half (*Aagg)[64][8] = (__half(*)[64][8])sm;             // 16 KB
    __half (*Ax)[64][8]   = (__half(*)[64][8])(sm + 16384);   // 16 KB
    __half (*Hs)[136]     = (__half(*)[136])sm;               // 17.4 KB (aliased)
    int tid = threadIdx.x;
    int n0  = blockIdx.x * 64;
    {
        int n  = tid & 63;
        int kg = tid >> 6;
        int ng = n0 + n;
        const uint4* pa = (const uint4*)(agg_h + (size_t)ng * 128 + kg * 32);
        const uint4* px = (const uint4*)(x_h   + (size_t)ng * 128 + kg * 32);
        #pragma unroll
        for (int i = 0; i < 4; ++i) {
            uint4 va = make_uint4(0, 0, 0, 0), vx = va;
            if (ng < N_NODES) { va = pa[i]; vx = px[i]; }
            *(uint4*)&Aagg[kg * 4 + i][n][0] = va;
            *(uint4*)&Ax[kg * 4 + i][n][0]   = vx;
        }
    }
    __syncthreads();
    int lane = tid & 63;
    int w = tid >> 6;
    int m = lane & 15;
    int q = lane >> 4;
    int row = w * 16 + m;
    const __half* bl0 = W1lf + (lane << 3);
    const __half* br0 = W1rf + (lane << 3);
    f32x4 accL[8], accR[8];
    #pragma unroll
    for (int c = 0; c < 8; ++c) {
        accL[c] = (f32x4){0.f, 0.f, 0.f, 0.f};
        accR[c] = (f32x4){0.f, 0.f, 0.f, 0.f};
    }
    #pragma unroll
    for (int ks = 0; ks < 4; ++ks) {
        f16x8 aL = *(const f16x8*)&Aagg[ks * 4 + q][row][0];
        f16x8 aR = *(const f16x8*)&Ax[ks * 4 + q][row][0];
        #pragma unroll
        for (int ct = 0; ct < 8; ++ct) {
            f16x8 bL = *(const f16x8*)(bl0 + ((ct * 4 + ks) << 9));
            f16x8 bR = *(const f16x8*)(br0 + ((ct * 4 + ks) << 9));
            accL[ct] = __builtin_amdgcn_mfma_f32_16x16x32_f16(aL, bL, accL[ct], 0, 0, 0);
            accR[ct] = __builtin_amdgcn_mfma_f32_16x16x32_f16(aR, bR, accR[ct], 0, 0, 0);
        }
    }
    float invd[4];
    #pragma unroll
    for (int r = 0; r < 4; ++r) {
        int n = n0 + w * 16 + q * 4 + r;
        int d = (n < N_NODES) ? counts[n] : 1;
        invd[r] = 1.0f / fmaxf((float)d, 1.0f);
    }
    __syncthreads();   // all A reads done before Hs overwrites the region
    #pragma unroll
    for (int ct = 0; ct < 8; ++ct) {
        int col = ct * 16 + m;
        float s = gamma[col] * rsqrtf(var[col] + 1e-5f);
        float t = beta[col] + (b1l[col] - mean[col]) * s;
        #pragma unroll
        for (int r = 0; r < 4; ++r) {
            float v = accL[ct][r] * invd[r] + accR[ct][r];
            v = fmaxf(v * s + t, 0.f);
            Hs[w * 16 + q * 4 + r][col] = __float2half(v);
        }
    }
    __syncthreads();
    {
        int rr = tid & 63;
        int pg = tid >> 6;
        int ng = n0 + rr;
        if (ng < N_NODES) {
            uint4* dst = (uint4*)(h_h + (size_t)ng * 128);
            #pragma unroll
            for (int i = 0; i < 4; ++i)
                dst[pg * 4 + i] = *(const uint4*)&Hs[rr][(pg * 4 + i) * 8];
        }
    }
}

// ---------------------------------------------------------------------------
// K-gemm2 (MFMA fp16): stacked fragment-ordered B = [W2l ; W2r]
// LDS: A-staging (16 KB) aliased with Cs (33.8 KB).
// ---------------------------------------------------------------------------
__global__ __launch_bounds__(256) void k_gemm2(
    const __half* __restrict__ h_h,
    const __half* __restrict__ W2f, const float* __restrict__ b2l,
    __half* __restrict__ p2, float* __restrict__ out)
{
    __shared__ char sm[33792];
    __half (*Ah)[64][8] = (__half(*)[64][8])sm;   // 16 KB
    float  (*Cs)[132]   = (float(*)[132])sm;      // 33.8 KB (aliased)
    int tid = threadIdx.x;
    int n0  = blockIdx.x * 64;
    {
        int n  = tid & 63;
        int kg = tid >> 6;
        int ng = n0 + n;
        const uint4* ph = (const uint4*)(h_h + (size_t)ng * 128 + kg * 32);
        #pragma unroll
        for (int i = 0; i < 4; ++i) {
            uint4 vh = make_uint4(0, 0, 0, 0);
            if (ng < N_NODES) vh = ph[i];
            *(uint4*)&Ah[kg * 4 + i][n][0] = vh;
        }
    }
    __syncthreads();
    int lane = tid & 63;
    int w = tid >> 6;
    int m = lane & 15;
    int q = lane >> 4;
    int row = w * 16 + m;
    const __half* b0 = W2f + (lane << 3);
    f32x4 acc[8];
    #pragma unroll
    for (int c = 0; c < 8; ++c) acc[c] = (f32x4){0.f, 0.f, 0.f, 0.f};
    #pragma unroll
    for (int ks = 0; ks < 4; ++ks) {
        f16x8 a = *(const f16x8*)&Ah[ks * 4 + q][row][0];
        #pragma unroll
        for (int ct = 0; ct < 8; ++ct) {
            f16x8 b = *(const f16x8*)(b0 + ((ct * 4 + ks) << 9));
            acc[ct] = __builtin_amdgcn_mfma_f32_16x16x32_f16(a, b, acc[ct], 0, 0, 0);
        }
    }
    __syncthreads();   // all Ah reads done before Cs overwrites the region
    #pragma unroll
    for (int ct = 0; ct < 8; ++ct) {
        int col = ct * 16 + m;
        #pragma unroll
        for (int r = 0; r < 4; ++r)
            Cs[w * 16 + q * 4 + r][col] = acc[ct][r];
    }
    __syncthreads();
    {
        int rr = tid & 63;
        int pg = tid >> 6;
        int ng = n0 + rr;
        if (ng < N_NODES) {
            union { __half hh[16]; uint4 u[2]; } tmp;
            #pragma unroll
            for (int c = 0; c < 16; ++c)
                tmp.hh[c] = __float2half(Cs[rr][pg * 16 + c]);
            uint4* dp = (uint4*)(p2 + (size_t)ng * 64 + pg * 16);
            dp[0] = tmp.u[0];
            dp[1] = tmp.u[1];
            #pragma unroll
            for (int i = 0; i < 4; ++i) {
                float4 v  = *(const float4*)&Cs[rr][64 + pg * 16 + i * 4];
                float4 bb = *(const float4*)(b2l + pg * 16 + i * 4);
                v.x += bb.x; v.y += bb.y; v.z += bb.z; v.w += bb.w;
                *(float4*)(out + (size_t)ng * 64 + pg * 16 + i * 4) = v;
            }
        }
    }
}

// ---------------------------------------------------------------------------
// K-agg2: out[n] += (sum_{e in row n} p2[csr_src[e]]) / max(deg,1)
// ---------------------------------------------------------------------------
__device__ __forceinline__ void acc_row_p2(
    const __half* __restrict__ p2, int s, int lane, float4& acc)
{
    uint2 u = ((const uint2*)(p2 + (size_t)s * 64))[lane];
    __half2 a = *(__half2*)&u.x;
    __half2 b = *(__half2*)&u.y;
    float2 fa = __half22float2(a);
    float2 fb = __half22float2(b);
    acc.x += fa.x; acc.y += fa.y; acc.z += fb.x; acc.w += fb.y;
}

__global__ __launch_bounds__(256) void k_agg2(
    const int* __restrict__ row_ptr, const int* __restrict__ csr_src,
    const __half* __restrict__ p2, float* __restrict__ out)
{
    int tid  = threadIdx.x;
    int n    = blockIdx.x * 16 + (tid >> 4);
    int lane = tid & 15;
    int e0 = row_ptr[n], e1 = row_ptr[n + 1];
    float4 acc = make_float4(0.f, 0.f, 0.f, 0.f);
    int e = e0;
    for (; e + 4 <= e1; e += 4) {
        int s0 = csr_src[e], s1 = csr_src[e + 1];
        int s2 = csr_src[e + 2], s3 = csr_src[e + 3];
        acc_row_p2(p2, s0, lane, acc);
        acc_row_p2(p2, s1, lane, acc);
        acc_row_p2(p2, s2, lane, acc);
        acc_row_p2(p2, s3, lane, acc);
    }
    for (; e < e1; ++e) acc_row_p2(p2, csr_src[e], lane, acc);
    float inv = 1.0f / fmaxf((float)(e1 - e0), 1.0f);
    float4* o = (float4*)out + n * 16 + lane;
    float4 cur = *o;
    cur.x += acc.x * inv; cur.y += acc.y * inv;
    cur.z += acc.z * inv; cur.w += acc.w * inv;
    *o = cur;
}

// ---------------------------------------------------------------------------
extern "C" void kernel_launch(void* const* d_in, const int* in_sizes, int n_in,
                              void* d_out, int out_size, void* d_ws, size_t ws_size,
                              hipStream_t stream)
{
    const float* x     = (const float*)d_in[0];
    const int*   ei    = (const int*)d_in[1];
    const float* W1l   = (const float*)d_in[2];
    const float* b1l   = (const float*)d_in[3];
    const float* W1r   = (const float*)d_in[4];
    const float* gamma = (const float*)d_in[5];
    const float* beta  = (const float*)d_in[6];
    const float* mean  = (const float*)d_in[7];
    const float* var   = (const float*)d_in[8];
    const float* W2l   = (const float*)d_in[9];
    const float* b2l   = (const float*)d_in[10];
    const float* W2r   = (const float*)d_in[11];
    float* out = (float*)d_out;

    char* ws = (char*)d_ws;
    __half* agg_h   = (__half*)(ws);                  // 25.6 MB (p2 aliases)
    __half* h_h     = (__half*)(ws + 25600000);       // 25.6 MB
    __half* x_h     = (__half*)(ws + 51200000);       // 25.6 MB
    int*    csr_src = (int*)(ws + 76800000);          // 6.4 MB
    int*    row_ptr = (int*)(ws + 83200000);          // 400 KB + 16
    int*    counts  = (int*)(ws + 83600016);          // 400 KB
    int*    cursor  = (int*)(ws + 84000016);          // 400 KB
    int*    blockSums = (int*)(ws + 84400016);        // 1 KB
    __half* W1lf    = (__half*)(ws + 84401040);       // 32 KB
    __half* W1rf    = (__half*)(ws + 84433808);       // 32 KB
    __half* W2f     = (__half*)(ws + 84466576);       // 32 KB
    int2*   ebuf    = (int2*)(ws + 84499344);         // 12.8 MB
    int*    bcur    = (int*)(ws + 97299344);          // 256 B
    __half* p2      = agg_h;

    hipMemsetAsync(counts, 0, N_NODES * sizeof(int), stream);
    k_hist<<<(N_EDGES + 255) / 256, 256, 0, stream>>>(ei, counts);
    k_tohalf<<<(N_NODES * 32 + 255) / 256, 256, 0, stream>>>(x, x_h);
    k_wfrag<<<192, 256, 0, stream>>>(W1l, W1r, W2l, W2r, W1lf, W1rf, W2f);
    k_scan1<<<SCAN_BLOCKS, 512, 0, stream>>>(counts, row_ptr, blockSums);
    k_scan2<<<1, 256, 0, stream>>>(blockSums);
    k_scan3<<<SCAN_BLOCKS, 512, 0, stream>>>(row_ptr, blockSums, cursor);
    k_bcur<<<1, 64, 0, stream>>>(row_ptr, bcur);
    k_binA<<<(N_EDGES + TILE - 1) / TILE, 256, 0, stream>>>(ei, bcur, ebuf);
    k_fillB<<<(N_EDGES + 255) / 256, 256, 0, stream>>>(ebuf, cursor, csr_src);
    k_agg1<<<N_NODES / 8, 256, 0, stream>>>(row_ptr, csr_src, x_h, agg_h);
    k_gemm1<<<(N_NODES + 63) / 64, 256, 0, stream>>>(agg_h, counts, x_h,
                                                     W1lf, b1l, W1rf,
                                                     gamma, beta, mean, var, h_h);
    k_gemm2<<<(N_NODES + 63) / 64, 256, 0, stream>>>(h_h, W2f, b2l, p2, out);
    k_agg2<<<N_NODES / 16, 256, 0, stream>>>(row_ptr, csr_src, p2, out);
}

// Round 7
// 408.685 us; speedup vs baseline: 1.5709x; 1.0663x over previous
//
#include <hip/hip_runtime.h>
#include <hip/hip_fp16.h>

#define N_NODES 100000
#define N_EDGES 1600000
#define SCAN_BLOCKS 196   // 196*512 = 100352 >= N_NODES
#define TILE 2048
#define NBUK 64
#define BSH 11            // bucket = dst >> 11 (2048 nodes/bucket, 49 used)
#define NBUK_USED ((N_NODES + (1 << BSH) - 1) >> BSH)   // 49

typedef _Float16 f16x8 __attribute__((ext_vector_type(8)));
typedef float    f32x4 __attribute__((ext_vector_type(4)));

// ---------------------------------------------------------------------------
// CSR build: histogram -> exclusive scan -> LDS-staged bin -> per-bucket fill
// ---------------------------------------------------------------------------
__global__ __launch_bounds__(256) void k_hist(
    const int* __restrict__ ei, int* __restrict__ counts)
{
    int e = blockIdx.x * 256 + threadIdx.x;
    if (e < N_EDGES) atomicAdd(&counts[ei[N_EDGES + e]], 1);
}

__global__ __launch_bounds__(512) void k_scan1(
    const int* __restrict__ counts, int* __restrict__ row_ptr,
    int* __restrict__ blockSums)
{
    __shared__ int s[512];
    int t = threadIdx.x;
    int i = blockIdx.x * 512 + t;
    int c = (i < N_NODES) ? counts[i] : 0;
    s[t] = c;
    __syncthreads();
    #pragma unroll
    for (int off = 1; off < 512; off <<= 1) {
        int v = (t >= off) ? s[t - off] : 0;
        __syncthreads();
        s[t] += v;
        __syncthreads();
    }
    if (i < N_NODES) row_ptr[i] = s[t] - c;
    if (t == 511) blockSums[blockIdx.x] = s[511];
}

__global__ __launch_bounds__(256) void k_scan2(int* __restrict__ blockSums)
{
    __shared__ int s[256];
    int t = threadIdx.x;
    int c = (t < SCAN_BLOCKS) ? blockSums[t] : 0;
    s[t] = c;
    __syncthreads();
    #pragma unroll
    for (int off = 1; off < 256; off <<= 1) {
        int v = (t >= off) ? s[t - off] : 0;
        __syncthreads();
        s[t] += v;
        __syncthreads();
    }
    if (t < SCAN_BLOCKS) blockSums[t] = s[t] - c;
}

__global__ __launch_bounds__(512) void k_scan3(
    int* __restrict__ row_ptr, const int* __restrict__ blockSums)
{
    int i = blockIdx.x * 512 + threadIdx.x;
    if (i < N_NODES) row_ptr[i] += blockSums[blockIdx.x];
    if (i == 0) row_ptr[N_NODES] = N_EDGES;
}

__global__ __launch_bounds__(64) void k_bcur(
    const int* __restrict__ row_ptr, int* __restrict__ bcur)
{
    int b = threadIdx.x;
    if (b < NBUK) bcur[b] = row_ptr[min(b << BSH, N_NODES)];
}

// Pass A: LDS-staged bucket partition (wavefront-coalesced writes)
__global__ __launch_bounds__(256) void k_binA(
    const int* __restrict__ ei, int* __restrict__ bcur,
    int2* __restrict__ ebuf)
{
    __shared__ int2 scratch[TILE];   // 16 KB
    __shared__ int hist[NBUK];
    __shared__ int tstart[NBUK];
    __shared__ int gbase[NBUK];
    int t = threadIdx.x;
    int e0 = blockIdx.x * TILE;
    int tile_n = min(TILE, N_EDGES - e0);
    if (t < NBUK) hist[t] = 0;
    __syncthreads();
    int srcs[8], dsts[8], rank[8], bks[8];
    #pragma unroll
    for (int i = 0; i < 8; ++i) {
        int e = e0 + i * 256 + t;
        bks[i] = -1;
        if (e < N_EDGES) {
            srcs[i] = ei[e];
            dsts[i] = ei[N_EDGES + e];
            bks[i]  = dsts[i] >> BSH;
            rank[i] = atomicAdd(&hist[bks[i]], 1);
        }
    }
    __syncthreads();
    if (t == 0) {
        int s = 0;
        #pragma unroll
        for (int b = 0; b < NBUK; ++b) { tstart[b] = s; s += hist[b]; }
    }
    __syncthreads();
    if (t < NBUK && hist[t] > 0)
        gbase[t] = atomicAdd(&bcur[t], hist[t]);
    __syncthreads();
    #pragma unroll
    for (int i = 0; i < 8; ++i)
        if (bks[i] >= 0)
            scratch[tstart[bks[i]] + rank[i]] = make_int2(srcs[i], dsts[i]);
    __syncthreads();
    for (int p = t; p < tile_n; p += 256) {
        int2 sd = scratch[p];
        int b = sd.y >> BSH;
        ebuf[gbase[b] + (p - tstart[b])] = sd;
    }
}

// Pass C: one workgroup per bucket. The bucket's csr_src window (~131 KB) is
// owned by exactly one block -> one XCD L2 -> lines accumulate all 16 entries
// before writeback (fixes the cross-XCD write amplification of the old fillB).
__global__ __launch_bounds__(1024) void k_fillC(
    const int2* __restrict__ ebuf, const int* __restrict__ row_ptr,
    int* __restrict__ csr_src)
{
    __shared__ int cur[1 << BSH];   // 8 KB node cursors
    int t = threadIdx.x;
    int base = blockIdx.x << BSH;
    for (int i = t; i < (1 << BSH); i += 1024) {
        int nb = base + i;
        cur[i] = (nb < N_NODES) ? row_ptr[nb] : 0;
    }
    __syncthreads();
    int p0 = row_ptr[base];
    int p1 = row_ptr[min(base + (1 << BSH), N_NODES)];
    for (int p = p0 + t; p < p1; p += 1024) {
        int2 sd = ebuf[p];
        int pos = atomicAdd(&cur[sd.y - base], 1);
        csr_src[pos] = sd.x;
    }
}

// ---------------------------------------------------------------------------
// dtype conversions
// ---------------------------------------------------------------------------
__global__ __launch_bounds__(256) void k_tohalf(
    const float* __restrict__ x, __half* __restrict__ x_h)
{
    int i = blockIdx.x * 256 + threadIdx.x;
    if (i < N_NODES * 32) {
        float4 v = ((const float4*)x)[i];
        __half2 a = __floats2half2_rn(v.x, v.y);
        __half2 b = __floats2half2_rn(v.z, v.w);
        uint2 u = make_uint2(*(unsigned*)&a, *(unsigned*)&b);
        ((uint2*)x_h)[i] = u;
    }
}

// Fragment-ordered fp16 weights (see round-6 note)
__global__ __launch_bounds__(256) void k_wfrag(
    const float* __restrict__ W1l, const float* __restrict__ W1r,
    const float* __restrict__ W2l, const float* __restrict__ W2r,
    __half* __restrict__ W1lf, __half* __restrict__ W1rf,
    __half* __restrict__ W2f)
{
    int t = blockIdx.x * 256 + threadIdx.x;
    if (t >= 49152) return;
    int tt = t & 16383;
    int j    = tt & 7;
    int lane = (tt >> 3) & 63;
    int ks   = (tt >> 9) & 3;
    int ct   = tt >> 11;
    int m = lane & 15, q = lane >> 4;
    int row = ct * 16 + m;
    int col = ks * 32 + q * 8 + j;
    if (t < 16384) {
        W1lf[tt] = __float2half(W1l[row * 128 + col]);
    } else if (t < 32768) {
        W1rf[tt] = __float2half(W1r[row * 128 + col]);
    } else {
        float v = (ct < 4) ? W2l[row * 128 + col]
                           : W2r[(row - 64) * 128 + col];
        W2f[tt] = __float2half(v);
    }
}

// ---------------------------------------------------------------------------
// K-agg1: agg_h[n] = sum_{e in row n} x_h[csr_src[e]]
// ---------------------------------------------------------------------------
__device__ __forceinline__ void acc_row_h(
    const __half* __restrict__ x_h, int s, int lane, float4& acc)
{
    uint2 u = ((const uint2*)(x_h + (size_t)s * 128))[lane];
    __half2 a = *(__half2*)&u.x;
    __half2 b = *(__half2*)&u.y;
    float2 fa = __half22float2(a);
    float2 fb = __half22float2(b);
    acc.x += fa.x; acc.y += fa.y; acc.z += fb.x; acc.w += fb.y;
}

__global__ __launch_bounds__(256) void k_agg1(
    const int* __restrict__ row_ptr, const int* __restrict__ csr_src,
    const __half* __restrict__ x_h, __half* __restrict__ agg_h)
{
    int tid  = threadIdx.x;
    int n    = blockIdx.x * 8 + (tid >> 5);
    int lane = tid & 31;
    int e0 = row_ptr[n], e1 = row_ptr[n + 1];
    float4 acc = make_float4(0.f, 0.f, 0.f, 0.f);
    int e = e0;
    for (; e + 4 <= e1; e += 4) {
        int s0 = csr_src[e], s1 = csr_src[e + 1];
        int s2 = csr_src[e + 2], s3 = csr_src[e + 3];
        acc_row_h(x_h, s0, lane, acc);
        acc_row_h(x_h, s1, lane, acc);
        acc_row_h(x_h, s2, lane, acc);
        acc_row_h(x_h, s3, lane, acc);
    }
    for (; e < e1; ++e) acc_row_h(x_h, csr_src[e], lane, acc);
    __half2 h0 = __floats2half2_rn(acc.x, acc.y);
    __half2 h1 = __floats2half2_rn(acc.z, acc.w);
    uint2 u = make_uint2(*(unsigned*)&h0, *(unsigned*)&h1);
    ((uint2*)agg_h)[n * 32 + lane] = u;
}

// ---------------------------------------------------------------------------
// K-gemm1 (MFMA fp16): h = relu(bn( (aggsum@W1l^T)*invdeg + x@W1r^T + b1l ))
// ---------------------------------------------------------------------------
__global__ __launch_bounds__(256) void k_gemm1(
    const __half* __restrict__ agg_h, const int* __restrict__ counts,
    const __half* __restrict__ x_h,
    const __half* __restrict__ W1lf, const float* __restrict__ b1l,
    const __half* __restrict__ W1rf,
    const float* __restrict__ gamma, const float* __restrict__ beta,
    const float* __restrict__ mean, const float* __restrict__ var,
    __half* __restrict__ h_h)
{
    __shared__ char sm[32768];
    __half (*Aagg)[64][8] = (__half(*)[64][8])sm;             // 16 KB
    __half (*Ax)[64][8]   = (__half(*)[64][8])(sm + 16384);   // 16 KB
    __half (*Hs)[136]     = (__half(*)[136])sm;               // 17.4 KB (aliased)
    int tid = threadIdx.x;
    int n0  = blockIdx.x * 64;
    {
        int n  = tid & 63;
        int kg = tid >> 6;
        int ng = n0 + n;
        const uint4* pa = (const uint4*)(agg_h + (size_t)ng * 128 + kg * 32);
        const uint4* px = (const uint4*)(x_h   + (size_t)ng * 128 + kg * 32);
        #pragma unroll
        for (int i = 0; i < 4; ++i) {
            uint4 va = make_uint4(0, 0, 0, 0), vx = va;
            if (ng < N_NODES) { va = pa[i]; vx = px[i]; }
            *(uint4*)&Aagg[kg * 4 + i][n][0] = va;
            *(uint4*)&Ax[kg * 4 + i][n][0]   = vx;
        }
    }
    __syncthreads();
    int lane = tid & 63;
    int w = tid >> 6;
    int m = lane & 15;
    int q = lane >> 4;
    int row = w * 16 + m;
    const __half* bl0 = W1lf + (lane << 3);
    const __half* br0 = W1rf + (lane << 3);
    f32x4 accL[8], accR[8];
    #pragma unroll
    for (int c = 0; c < 8; ++c) {
        accL[c] = (f32x4){0.f, 0.f, 0.f, 0.f};
        accR[c] = (f32x4){0.f, 0.f, 0.f, 0.f};
    }
    #pragma unroll
    for (int ks = 0; ks < 4; ++ks) {
        f16x8 aL = *(const f16x8*)&Aagg[ks * 4 + q][row][0];
        f16x8 aR = *(const f16x8*)&Ax[ks * 4 + q][row][0];
        #pragma unroll
        for (int ct = 0; ct < 8; ++ct) {
            f16x8 bL = *(const f16x8*)(bl0 + ((ct * 4 + ks) << 9));
            f16x8 bR = *(const f16x8*)(br0 + ((ct * 4 + ks) << 9));
            accL[ct] = __builtin_amdgcn_mfma_f32_16x16x32_f16(aL, bL, accL[ct], 0, 0, 0);
            accR[ct] = __builtin_amdgcn_mfma_f32_16x16x32_f16(aR, bR, accR[ct], 0, 0, 0);
        }
    }
    float invd[4];
    #pragma unroll
    for (int r = 0; r < 4; ++r) {
        int n = n0 + w * 16 + q * 4 + r;
        int d = (n < N_NODES) ? counts[n] : 1;
        invd[r] = 1.0f / fmaxf((float)d, 1.0f);
    }
    __syncthreads();   // all A reads done before Hs overwrites the region
    #pragma unroll
    for (int ct = 0; ct < 8; ++ct) {
        int col = ct * 16 + m;
        float s = gamma[col] * rsqrtf(var[col] + 1e-5f);
        float t = beta[col] + (b1l[col] - mean[col]) * s;
        #pragma unroll
        for (int r = 0; r < 4; ++r) {
            float v = accL[ct][r] * invd[r] + accR[ct][r];
            v = fmaxf(v * s + t, 0.f);
            Hs[w * 16 + q * 4 + r][col] = __float2half(v);
        }
    }
    __syncthreads();
    {
        int rr = tid & 63;
        int pg = tid >> 6;
        int ng = n0 + rr;
        if (ng < N_NODES) {
            uint4* dst = (uint4*)(h_h + (size_t)ng * 128);
            #pragma unroll
            for (int i = 0; i < 4; ++i)
                dst[pg * 4 + i] = *(const uint4*)&Hs[rr][(pg * 4 + i) * 8];
        }
    }
}

// ---------------------------------------------------------------------------
// K-gemm2 (MFMA fp16): stacked fragment-ordered B = [W2l ; W2r]
// ---------------------------------------------------------------------------
__global__ __launch_bounds__(256) void k_gemm2(
    const __half* __restrict__ h_h,
    const __half* __restrict__ W2f, const float* __restrict__ b2l,
    __half* __restrict__ p2, float* __restrict__ out)
{
    __shared__ char sm[33792];
    __half (*Ah)[64][8] = (__half(*)[64][8])sm;   // 16 KB
    float  (*Cs)[132]   = (float(*)[132])sm;      // 33.8 KB (aliased)
    int tid = threadIdx.x;
    int n0  = blockIdx.x * 64;
    {
        int n  = tid & 63;
        int kg = tid >> 6;
        int ng = n0 + n;
        const uint4* ph = (const uint4*)(h_h + (size_t)ng * 128 + kg * 32);
        #pragma unroll
        for (int i = 0; i < 4; ++i) {
            uint4 vh = make_uint4(0, 0, 0, 0);
            if (ng < N_NODES) vh = ph[i];
            *(uint4*)&Ah[kg * 4 + i][n][0] = vh;
        }
    }
    __syncthreads();
    int lane = tid & 63;
    int w = tid >> 6;
    int m = lane & 15;
    int q = lane >> 4;
    int row = w * 16 + m;
    const __half* b0 = W2f + (lane << 3);
    f32x4 acc[8];
    #pragma unroll
    for (int c = 0; c < 8; ++c) acc[c] = (f32x4){0.f, 0.f, 0.f, 0.f};
    #pragma unroll
    for (int ks = 0; ks < 4; ++ks) {
        f16x8 a = *(const f16x8*)&Ah[ks * 4 + q][row][0];
        #pragma unroll
        for (int ct = 0; ct < 8; ++ct) {
            f16x8 b = *(const f16x8*)(b0 + ((ct * 4 + ks) << 9));
            acc[ct] = __builtin_amdgcn_mfma_f32_16x16x32_f16(a, b, acc[ct], 0, 0, 0);
        }
    }
    __syncthreads();   // all Ah reads done before Cs overwrites the region
    #pragma unroll
    for (int ct = 0; ct < 8; ++ct) {
        int col = ct * 16 + m;
        #pragma unroll
        for (int r = 0; r < 4; ++r)
            Cs[w * 16 + q * 4 + r][col] = acc[ct][r];
    }
    __syncthreads();
    {
        int rr = tid & 63;
        int pg = tid >> 6;
        int ng = n0 + rr;
        if (ng < N_NODES) {
            union { __half hh[16]; uint4 u[2]; } tmp;
            #pragma unroll
            for (int c = 0; c < 16; ++c)
                tmp.hh[c] = __float2half(Cs[rr][pg * 16 + c]);
            uint4* dp = (uint4*)(p2 + (size_t)ng * 64 + pg * 16);
            dp[0] = tmp.u[0];
            dp[1] = tmp.u[1];
            #pragma unroll
            for (int i = 0; i < 4; ++i) {
                float4 v  = *(const float4*)&Cs[rr][64 + pg * 16 + i * 4];
                float4 bb = *(const float4*)(b2l + pg * 16 + i * 4);
                v.x += bb.x; v.y += bb.y; v.z += bb.z; v.w += bb.w;
                *(float4*)(out + (size_t)ng * 64 + pg * 16 + i * 4) = v;
            }
        }
    }
}

// ---------------------------------------------------------------------------
// K-agg2: out[n] += (sum_{e in row n} p2[csr_src[e]]) / max(deg,1)
// ---------------------------------------------------------------------------
__device__ __forceinline__ void acc_row_p2(
    const __half* __restrict__ p2, int s, int lane, float4& acc)
{
    uint2 u = ((const uint2*)(p2 + (size_t)s * 64))[lane];
    __half2 a = *(__half2*)&u.x;
    __half2 b = *(__half2*)&u.y;
    float2 fa = __half22float2(a);
    float2 fb = __half22float2(b);
    acc.x += fa.x; acc.y += fa.y; acc.z += fb.x; acc.w += fb.y;
}

__global__ __launch_bounds__(256) void k_agg2(
    const int* __restrict__ row_ptr, const int* __restrict__ csr_src,
    const __half* __restrict__ p2, float* __restrict__ out)
{
    int tid  = threadIdx.x;
    int n    = blockIdx.x * 16 + (tid >> 4);
    int lane = tid & 15;
    int e0 = row_ptr[n], e1 = row_ptr[n + 1];
    float4 acc = make_float4(0.f, 0.f, 0.f, 0.f);
    int e = e0;
    for (; e + 4 <= e1; e += 4) {
        int s0 = csr_src[e], s1 = csr_src[e + 1];
        int s2 = csr_src[e + 2], s3 = csr_src[e + 3];
        acc_row_p2(p2, s0, lane, acc);
        acc_row_p2(p2, s1, lane, acc);
        acc_row_p2(p2, s2, lane, acc);
        acc_row_p2(p2, s3, lane, acc);
    }
    for (; e < e1; ++e) acc_row_p2(p2, csr_src[e], lane, acc);
    float inv = 1.0f / fmaxf((float)(e1 - e0), 1.0f);
    float4* o = (float4*)out + n * 16 + lane;
    float4 cur = *o;
    cur.x += acc.x * inv; cur.y += acc.y * inv;
    cur.z += acc.z * inv; cur.w += acc.w * inv;
    *o = cur;
}

// ---------------------------------------------------------------------------
extern "C" void kernel_launch(void* const* d_in, const int* in_sizes, int n_in,
                              void* d_out, int out_size, void* d_ws, size_t ws_size,
                              hipStream_t stream)
{
    const float* x     = (const float*)d_in[0];
    const int*   ei    = (const int*)d_in[1];
    const float* W1l   = (const float*)d_in[2];
    const float* b1l   = (const float*)d_in[3];
    const float* W1r   = (const float*)d_in[4];
    const float* gamma = (const float*)d_in[5];
    const float* beta  = (const float*)d_in[6];
    const float* mean  = (const float*)d_in[7];
    const float* var   = (const float*)d_in[8];
    const float* W2l   = (const float*)d_in[9];
    const float* b2l   = (const float*)d_in[10];
    const float* W2r   = (const float*)d_in[11];
    float* out = (float*)d_out;

    char* ws = (char*)d_ws;
    __half* agg_h   = (__half*)(ws);                  // 25.6 MB (p2 aliases)
    __half* h_h     = (__half*)(ws + 25600000);       // 25.6 MB
    __half* x_h     = (__half*)(ws + 51200000);       // 25.6 MB
    int*    csr_src = (int*)(ws + 76800000);          // 6.4 MB
    int*    row_ptr = (int*)(ws + 83200000);          // 400 KB + 16
    int*    counts  = (int*)(ws + 83600016);          // 400 KB
    int*    blockSums = (int*)(ws + 84400016);        // 1 KB
    __half* W1lf    = (__half*)(ws + 84401040);       // 32 KB
    __half* W1rf    = (__half*)(ws + 84433808);       // 32 KB
    __half* W2f     = (__half*)(ws + 84466576);       // 32 KB
    int2*   ebuf    = (int2*)(ws + 84499344);         // 12.8 MB
    int*    bcur    = (int*)(ws + 97299344);          // 256 B
    __half* p2      = agg_h;

    hipMemsetAsync(counts, 0, N_NODES * sizeof(int), stream);
    k_hist<<<(N_EDGES + 255) / 256, 256, 0, stream>>>(ei, counts);
    k_tohalf<<<(N_NODES * 32 + 255) / 256, 256, 0, stream>>>(x, x_h);
    k_wfrag<<<192, 256, 0, stream>>>(W1l, W1r, W2l, W2r, W1lf, W1rf, W2f);
    k_scan1<<<SCAN_BLOCKS, 512, 0, stream>>>(counts, row_ptr, blockSums);
    k_scan2<<<1, 256, 0, stream>>>(blockSums);
    k_scan3<<<SCAN_BLOCKS, 512, 0, stream>>>(row_ptr, blockSums);
    k_bcur<<<1, 64, 0, stream>>>(row_ptr, bcur);
    k_binA<<<(N_EDGES + TILE - 1) / TILE, 256, 0, stream>>>(ei, bcur, ebuf);
    k_fillC<<<NBUK_USED, 1024, 0, stream>>>(ebuf, row_ptr, csr_src);
    k_agg1<<<N_NODES / 8, 256, 0, stream>>>(row_ptr, csr_src, x_h, agg_h);
    k_gemm1<<<(N_NODES + 63) / 64, 256, 0, stream>>>(agg_h, counts, x_h,
                                                     W1lf, b1l, W1rf,
                                                     gamma, beta, mean, var, h_h);
    k_gemm2<<<(N_NODES + 63) / 64, 256, 0, stream>>>(h_h, W2f, b2l, p2, out);
    k_agg2<<<N_NODES / 16, 256, 0, stream>>>(row_ptr, csr_src, p2, out);
}

// Round 9
// 335.174 us; speedup vs baseline: 1.9154x; 1.2193x over previous
//
#include <hip/hip_runtime.h>
#include <hip/hip_fp16.h>

#define N_NODES 100000
#define N_EDGES 1600000
#define TILE 2048
#define NBUK 64
#define BSH 11            // bucket = dst >> 11 (2048 nodes/bucket, 49 used)
#define NBUK_USED ((N_NODES + (1 << BSH) - 1) >> BSH)   // 49
#define CAP 36864         // fixed ebuf region per bucket (mean 32768, sigma~179)
#define SMASK 0x1FFFF     // node-id guard mask (identity for id < 131072)

typedef _Float16 f16x8 __attribute__((ext_vector_type(8)));
typedef float    f32x4 __attribute__((ext_vector_type(4)));

// ---------------------------------------------------------------------------
// CSR build: fixed-region LDS-staged bin -> tiny bucket scan -> per-bucket
// local histogram + scan + fill.  All data-dependent indices are guarded
// (mask/min) so bad data degrades to wrong-answer, never a fault.
// ---------------------------------------------------------------------------
__global__ __launch_bounds__(64) void k_binit(int* __restrict__ bcur)
{
    int t = threadIdx.x;
    if (t < NBUK) bcur[t] = t * CAP;
}

__global__ __launch_bounds__(256) void k_binA(
    const int* __restrict__ ei, int* __restrict__ bcur,
    int2* __restrict__ ebuf)
{
    __shared__ int2 scratch[TILE];   // 16 KB
    __shared__ int hist[NBUK];
    __shared__ int tstart[NBUK];
    __shared__ int gbase[NBUK];
    int t = threadIdx.x;
    int e0 = blockIdx.x * TILE;
    int tile_n = min(TILE, N_EDGES - e0);
    if (t < NBUK) hist[t] = 0;
    __syncthreads();
    int srcs[8], dsts[8], rank[8], bks[8];
    #pragma unroll
    for (int i = 0; i < 8; ++i) {
        int e = e0 + i * 256 + t;
        bks[i] = -1;
        if (e < N_EDGES) {
            srcs[i] = ei[e];
            dsts[i] = ei[N_EDGES + e];
            bks[i]  = (dsts[i] >> BSH) & (NBUK - 1);   // guarded
            rank[i] = atomicAdd(&hist[bks[i]], 1);
        }
    }
    __syncthreads();
    if (t == 0) {
        int s = 0;
        #pragma unroll
        for (int b = 0; b < NBUK; ++b) { tstart[b] = s; s += hist[b]; }
    }
    __syncthreads();
    if (t < NBUK && hist[t] > 0)
        gbase[t] = atomicAdd(&bcur[t], hist[t]);
    __syncthreads();
    #pragma unroll
    for (int i = 0; i < 8; ++i)
        if (bks[i] >= 0) {
            int sl = tstart[bks[i]] + rank[i];
            scratch[min(sl, TILE - 1)] = make_int2(srcs[i], dsts[i]);
        }
    __syncthreads();
    for (int p = t; p < tile_n; p += 256) {
        int2 sd = scratch[p];
        int b = (sd.y >> BSH) & (NBUK - 1);
        int o = gbase[b] + (p - tstart[b]);
        ebuf[min(max(o, 0), NBUK * CAP - 1)] = sd;     // guarded
    }
}

// exclusive scan of the 49 bucket counts -> bbase[0..49]
__global__ __launch_bounds__(64) void k_scanb(
    const int* __restrict__ bcur, int* __restrict__ bbase)
{
    __shared__ int s[64];
    int t = threadIdx.x;
    int c = (t < NBUK_USED) ? (bcur[t] - t * CAP) : 0;
    c = min(max(c, 0), CAP);                           // guarded
    s[t] = c;
    __syncthreads();
    #pragma unroll
    for (int off = 1; off < 64; off <<= 1) {
        int v = (t >= off) ? s[t - off] : 0;
        __syncthreads();
        s[t] += v;
        __syncthreads();
    }
    if (t < NBUK_USED) bbase[t] = s[t] - c;
    if (t == NBUK_USED - 1) bbase[NBUK_USED] = s[t];
}

// one block per bucket: LDS per-node histogram + pair-scan (writes the
// bucket's row_ptr slice) + LDS-cursor fine fill into the block-owned
// csr_src window (single-XCD L2 write locality).
__global__ __launch_bounds__(1024) void k_fillC2(
    const int2* __restrict__ ebuf, const int* __restrict__ bbase,
    int* __restrict__ row_ptr, int* __restrict__ csr_src)
{
    __shared__ int hist[1 << BSH];   // 8 KB
    __shared__ int psum[1024];       // 4 KB
    __shared__ int cur[1 << BSH];    // 8 KB
    int t = threadIdx.x;
    int b = blockIdx.x;
    int base = b << BSH;
    hist[t] = 0;
    hist[t + 1024] = 0;
    __syncthreads();
    int bb  = bbase[b];
    int cnt = min(bbase[b + 1] - bb, CAP);             // guarded
    const int2* eb = ebuf + (size_t)b * CAP;
    for (int p = t; p < cnt; p += 1024)
        atomicAdd(&hist[(eb[p].y - base) & ((1 << BSH) - 1)], 1);   // guarded
    __syncthreads();
    int h0 = hist[2 * t], h1 = hist[2 * t + 1];
    psum[t] = h0 + h1;
    __syncthreads();
    #pragma unroll
    for (int off = 1; off < 1024; off <<= 1) {
        int v = (t >= off) ? psum[t - off] : 0;
        __syncthreads();
        psum[t] += v;
        __syncthreads();
    }
    int e0 = bb + psum[t] - (h0 + h1);   // exclusive over this bucket
    int e1 = e0 + h0;
    int n0g = base + 2 * t, n1g = n0g + 1;
    if (n0g <= N_NODES) row_ptr[n0g] = e0;
    if (n1g <= N_NODES) row_ptr[n1g] = e1;
    cur[2 * t]     = e0;
    cur[2 * t + 1] = e1;
    __syncthreads();
    for (int p = t; p < cnt; p += 1024) {
        int2 sd = eb[p];
        int pos = atomicAdd(&cur[(sd.y - base) & ((1 << BSH) - 1)], 1);
        csr_src[min(max(pos, 0), N_EDGES - 1)] = sd.x;  // guarded
    }
}

// ---------------------------------------------------------------------------
// dtype conversions
// ---------------------------------------------------------------------------
__global__ __launch_bounds__(256) void k_tohalf(
    const float* __restrict__ x, __half* __restrict__ x_h)
{
    int i = blockIdx.x * 256 + threadIdx.x;
    if (i < N_NODES * 32) {
        float4 v = ((const float4*)x)[i];
        __half2 a = __floats2half2_rn(v.x, v.y);
        __half2 b = __floats2half2_rn(v.z, v.w);
        uint2 u = make_uint2(*(unsigned*)&a, *(unsigned*)&b);
        ((uint2*)x_h)[i] = u;
    }
}

// Fragment-ordered fp16 weights (round-6 note)
__global__ __launch_bounds__(256) void k_wfrag(
    const float* __restrict__ W1l, const float* __restrict__ W1r,
    const float* __restrict__ W2l, const float* __restrict__ W2r,
    __half* __restrict__ W1lf, __half* __restrict__ W1rf,
    __half* __restrict__ W2f)
{
    int t = blockIdx.x * 256 + threadIdx.x;
    if (t >= 49152) return;
    int tt = t & 16383;
    int j    = tt & 7;
    int lane = (tt >> 3) & 63;
    int ks   = (tt >> 9) & 3;
    int ct   = tt >> 11;
    int m = lane & 15, q = lane >> 4;
    int row = ct * 16 + m;
    int col = ks * 32 + q * 8 + j;
    if (t < 16384) {
        W1lf[tt] = __float2half(W1l[row * 128 + col]);
    } else if (t < 32768) {
        W1rf[tt] = __float2half(W1r[row * 128 + col]);
    } else {
        float v = (ct < 4) ? W2l[row * 128 + col]
                           : W2r[(row - 64) * 128 + col];
        W2f[tt] = __float2half(v);
    }
}

// ---------------------------------------------------------------------------
// K-agg1: agg_h[n] = sum_{e in row n} x_h[csr_src[e]]
// ---------------------------------------------------------------------------
__device__ __forceinline__ void acc_row_h(
    const __half* __restrict__ x_h, int s, int lane, float4& acc)
{
    uint2 u = ((const uint2*)(x_h + (size_t)(s & SMASK) * 128))[lane];
    __half2 a = *(__half2*)&u.x;
    __half2 b = *(__half2*)&u.y;
    float2 fa = __half22float2(a);
    float2 fb = __half22float2(b);
    acc.x += fa.x; acc.y += fa.y; acc.z += fb.x; acc.w += fb.y;
}

__global__ __launch_bounds__(256) void k_agg1(
    const int* __restrict__ row_ptr, const int* __restrict__ csr_src,
    const __half* __restrict__ x_h, __half* __restrict__ agg_h)
{
    int tid  = threadIdx.x;
    int n    = blockIdx.x * 8 + (tid >> 5);
    int lane = tid & 31;
    int e1 = min(row_ptr[n + 1], N_EDGES);             // guarded
    int e0 = min(max(row_ptr[n], 0), e1);
    float4 acc = make_float4(0.f, 0.f, 0.f, 0.f);
    int e = e0;
    for (; e + 4 <= e1; e += 4) {
        int s0 = csr_src[e], s1 = csr_src[e + 1];
        int s2 = csr_src[e + 2], s3 = csr_src[e + 3];
        acc_row_h(x_h, s0, lane, acc);
        acc_row_h(x_h, s1, lane, acc);
        acc_row_h(x_h, s2, lane, acc);
        acc_row_h(x_h, s3, lane, acc);
    }
    for (; e < e1; ++e) acc_row_h(x_h, csr_src[e], lane, acc);
    __half2 h0 = __floats2half2_rn(acc.x, acc.y);
    __half2 h1 = __floats2half2_rn(acc.z, acc.w);
    uint2 u = make_uint2(*(unsigned*)&h0, *(unsigned*)&h1);
    ((uint2*)agg_h)[n * 32 + lane] = u;
}

// ---------------------------------------------------------------------------
// K-gemm1 (MFMA fp16): h = relu(bn( (aggsum@W1l^T)*invdeg + x@W1r^T + b1l ))
// deg from row_ptr diffs.
// ---------------------------------------------------------------------------
__global__ __launch_bounds__(256) void k_gemm1(
    const __half* __restrict__ agg_h, const int* __restrict__ row_ptr,
    const __half* __restrict__ x_h,
    const __half* __restrict__ W1lf, const float* __restrict__ b1l,
    const __half* __restrict__ W1rf,
    const float* __restrict__ gamma, const float* __restrict__ beta,
    const float* __restrict__ mean, const float* __restrict__ var,
    __half* __restrict__ h_h)
{
    __shared__ char sm[32768];
    __half (*Aagg)[64][8] = (__half(*)[64][8])sm;             // 16 KB
    __half (*Ax)[64][8]   = (__half(*)[64][8])(sm + 16384);   // 16 KB
    __half (*Hs)[136]     = (__half(*)[136])sm;               // 17.4 KB (aliased)
    int tid = threadIdx.x;
    int n0  = blockIdx.x * 64;
    {
        int n  = tid & 63;
        int kg = tid >> 6;
        int ng = n0 + n;
        const uint4* pa = (const uint4*)(agg_h + (size_t)ng * 128 + kg * 32);
        const uint4* px = (const uint4*)(x_h   + (size_t)ng * 128 + kg * 32);
        #pragma unroll
        for (int i = 0; i < 4; ++i) {
            uint4 va = make_uint4(0, 0, 0, 0), vx = va;
            if (ng < N_NODES) { va = pa[i]; vx = px[i]; }
            *(uint4*)&Aagg[kg * 4 + i][n][0] = va;
            *(uint4*)&Ax[kg * 4 + i][n][0]   = vx;
        }
    }
    __syncthreads();
    int lane = tid & 63;
    int w = tid >> 6;
    int m = lane & 15;
    int q = lane >> 4;
    int row = w * 16 + m;
    const __half* bl0 = W1lf + (lane << 3);
    const __half* br0 = W1rf + (lane << 3);
    f32x4 accL[8], accR[8];
    #pragma unroll
    for (int c = 0; c < 8; ++c) {
        accL[c] = (f32x4){0.f, 0.f, 0.f, 0.f};
        accR[c] = (f32x4){0.f, 0.f, 0.f, 0.f};
    }
    #pragma unroll
    for (int ks = 0; ks < 4; ++ks) {
        f16x8 aL = *(const f16x8*)&Aagg[ks * 4 + q][row][0];
        f16x8 aR = *(const f16x8*)&Ax[ks * 4 + q][row][0];
        #pragma unroll
        for (int ct = 0; ct < 8; ++ct) {
            f16x8 bL = *(const f16x8*)(bl0 + ((ct * 4 + ks) << 9));
            f16x8 bR = *(const f16x8*)(br0 + ((ct * 4 + ks) << 9));
            accL[ct] = __builtin_amdgcn_mfma_f32_16x16x32_f16(aL, bL, accL[ct], 0, 0, 0);
            accR[ct] = __builtin_amdgcn_mfma_f32_16x16x32_f16(aR, bR, accR[ct], 0, 0, 0);
        }
    }
    float invd[4];
    #pragma unroll
    for (int r = 0; r < 4; ++r) {
        int n = n0 + w * 16 + q * 4 + r;
        int d = (n < N_NODES) ? (row_ptr[n + 1] - row_ptr[n]) : 1;
        invd[r] = 1.0f / fmaxf((float)d, 1.0f);
    }
    __syncthreads();   // all A reads done before Hs overwrites the region
    #pragma unroll
    for (int ct = 0; ct < 8; ++ct) {
        int col = ct * 16 + m;
        float s = gamma[col] * rsqrtf(var[col] + 1e-5f);
        float t = beta[col] + (b1l[col] - mean[col]) * s;
        #pragma unroll
        for (int r = 0; r < 4; ++r) {
            float v = accL[ct][r] * invd[r] + accR[ct][r];
            v = fmaxf(v * s + t, 0.f);
            Hs[w * 16 + q * 4 + r][col] = __float2half(v);
        }
    }
    __syncthreads();
    {
        int rr = tid & 63;
        int pg = tid >> 6;
        int ng = n0 + rr;
        if (ng < N_NODES) {
            uint4* dst = (uint4*)(h_h + (size_t)ng * 128);
            #pragma unroll
            for (int i = 0; i < 4; ++i)
                dst[pg * 4 + i] = *(const uint4*)&Hs[rr][(pg * 4 + i) * 8];
        }
    }
}

// ---------------------------------------------------------------------------
// K-gemm2 (MFMA fp16): stacked fragment-ordered B = [W2l ; W2r]
// ---------------------------------------------------------------------------
__global__ __launch_bounds__(256) void k_gemm2(
    const __half* __restrict__ h_h,
    const __half* __restrict__ W2f, const float* __restrict__ b2l,
    __half* __restrict__ p2, float* __restrict__ out)
{
    __shared__ char sm[33792];
    __half (*Ah)[64][8] = (__half(*)[64][8])sm;   // 16 KB
    float  (*Cs)[132]   = (float(*)[132])sm;      // 33.8 KB (aliased)
    int tid = threadIdx.x;
    int n0  = blockIdx.x * 64;
    {
        int n  = tid & 63;
        int kg = tid >> 6;
        int ng = n0 + n;
        const uint4* ph = (const uint4*)(h_h + (size_t)ng * 128 + kg * 32);
        #pragma unroll
        for (int i = 0; i < 4; ++i) {
            uint4 vh = make_uint4(0, 0, 0, 0);
            if (ng < N_NODES) vh = ph[i];
            *(uint4*)&Ah[kg * 4 + i][n][0] = vh;
        }
    }
    __syncthreads();
    int lane = tid & 63;
    int w = tid >> 6;
    int m = lane & 15;
    int q = lane >> 4;
    int row = w * 16 + m;
    const __half* b0 = W2f + (lane << 3);
    f32x4 acc[8];
    #pragma unroll
    for (int c = 0; c < 8; ++c) acc[c] = (f32x4){0.f, 0.f, 0.f, 0.f};
    #pragma unroll
    for (int ks = 0; ks < 4; ++ks) {
        f16x8 a = *(const f16x8*)&Ah[ks * 4 + q][row][0];
        #pragma unroll
        for (int ct = 0; ct < 8; ++ct) {
            f16x8 b = *(const f16x8*)(b0 + ((ct * 4 + ks) << 9));
            acc[ct] = __builtin_amdgcn_mfma_f32_16x16x32_f16(a, b, acc[ct], 0, 0, 0);
        }
    }
    __syncthreads();   // all Ah reads done before Cs overwrites the region
    #pragma unroll
    for (int ct = 0; ct < 8; ++ct) {
        int col = ct * 16 + m;
        #pragma unroll
        for (int r = 0; r < 4; ++r)
            Cs[w * 16 + q * 4 + r][col] = acc[ct][r];
    }
    __syncthreads();
    {
        int rr = tid & 63;
        int pg = tid >> 6;
        int ng = n0 + rr;
        if (ng < N_NODES) {
            union { __half hh[16]; uint4 u[2]; } tmp;
            #pragma unroll
            for (int c = 0; c < 16; ++c)
                tmp.hh[c] = __float2half(Cs[rr][pg * 16 + c]);
            uint4* dp = (uint4*)(p2 + (size_t)ng * 64 + pg * 16);
            dp[0] = tmp.u[0];
            dp[1] = tmp.u[1];
            #pragma unroll
            for (int i = 0; i < 4; ++i) {
                float4 v  = *(const float4*)&Cs[rr][64 + pg * 16 + i * 4];
                float4 bb = *(const float4*)(b2l + pg * 16 + i * 4);
                v.x += bb.x; v.y += bb.y; v.z += bb.z; v.w += bb.w;
                *(float4*)(out + (size_t)ng * 64 + pg * 16 + i * 4) = v;
            }
        }
    }
}

// ---------------------------------------------------------------------------
// K-agg2: out[n] += (sum_{e in row n} p2[csr_src[e]]) / max(deg,1)
// ---------------------------------------------------------------------------
__device__ __forceinline__ void acc_row_p2(
    const __half* __restrict__ p2, int s, int lane, float4& acc)
{
    uint2 u = ((const uint2*)(p2 + (size_t)(s & SMASK) * 64))[lane];
    __half2 a = *(__half2*)&u.x;
    __half2 b = *(__half2*)&u.y;
    float2 fa = __half22float2(a);
    float2 fb = __half22float2(b);
    acc.x += fa.x; acc.y += fa.y; acc.z += fb.x; acc.w += fb.y;
}

__global__ __launch_bounds__(256) void k_agg2(
    const int* __restrict__ row_ptr, const int* __restrict__ csr_src,
    const __half* __restrict__ p2, float* __restrict__ out)
{
    int tid  = threadIdx.x;
    int n    = blockIdx.x * 16 + (tid >> 4);
    int lane = tid & 15;
    int e1 = min(row_ptr[n + 1], N_EDGES);             // guarded
    int e0 = min(max(row_ptr[n], 0), e1);
    float4 acc = make_float4(0.f, 0.f, 0.f, 0.f);
    int e = e0;
    for (; e + 4 <= e1; e += 4) {
        int s0 = csr_src[e], s1 = csr_src[e + 1];
        int s2 = csr_src[e + 2], s3 = csr_src[e + 3];
        acc_row_p2(p2, s0, lane, acc);
        acc_row_p2(p2, s1, lane, acc);
        acc_row_p2(p2, s2, lane, acc);
        acc_row_p2(p2, s3, lane, acc);
    }
    for (; e < e1; ++e) acc_row_p2(p2, csr_src[e], lane, acc);
    float inv = 1.0f / fmaxf((float)(e1 - e0), 1.0f);
    float4* o = (float4*)out + n * 16 + lane;
    float4 cur = *o;
    cur.x += acc.x * inv; cur.y += acc.y * inv;
    cur.z += acc.z * inv; cur.w += acc.w * inv;
    *o = cur;
}

// ---------------------------------------------------------------------------
extern "C" void kernel_launch(void* const* d_in, const int* in_sizes, int n_in,
                              void* d_out, int out_size, void* d_ws, size_t ws_size,
                              hipStream_t stream)
{
    const float* x     = (const float*)d_in[0];
    const int*   ei    = (const int*)d_in[1];
    const float* W1l   = (const float*)d_in[2];
    const float* b1l   = (const float*)d_in[3];
    const float* W1r   = (const float*)d_in[4];
    const float* gamma = (const float*)d_in[5];
    const float* beta  = (const float*)d_in[6];
    const float* mean  = (const float*)d_in[7];
    const float* var   = (const float*)d_in[8];
    const float* W2l   = (const float*)d_in[9];
    const float* b2l   = (const float*)d_in[10];
    const float* W2r   = (const float*)d_in[11];
    float* out = (float*)d_out;

    char* ws = (char*)d_ws;
    __half* agg_h   = (__half*)(ws);                  // 25.6 MB (p2 aliases)
    __half* h_h     = (__half*)(ws + 25600000);       // 25.6 MB
    __half* x_h     = (__half*)(ws + 51200000);       // 25.6 MB
    int*    csr_src = (int*)(ws + 76800000);          // 6.4 MB
    int*    row_ptr = (int*)(ws + 83200000);          // 400 KB + 16
    __half* W1lf    = (__half*)(ws + 83600016);       // 32 KB
    __half* W1rf    = (__half*)(ws + 83632784);       // 32 KB
    __half* W2f     = (__half*)(ws + 83665552);       // 32 KB
    int2*   ebuf    = (int2*)(ws + 83698320);         // 18.87 MB (64*CAP*8)
    int*    bcur    = (int*)(ws + 102572688);         // 256 B
    int*    bbase   = (int*)(ws + 102572944);         // 256 B
    __half* p2      = agg_h;

    k_binit<<<1, 64, 0, stream>>>(bcur);
    k_tohalf<<<(N_NODES * 32 + 255) / 256, 256, 0, stream>>>(x, x_h);
    k_wfrag<<<192, 256, 0, stream>>>(W1l, W1r, W2l, W2r, W1lf, W1rf, W2f);
    k_binA<<<(N_EDGES + TILE - 1) / TILE, 256, 0, stream>>>(ei, bcur, ebuf);
    k_scanb<<<1, 64, 0, stream>>>(bcur, bbase);
    k_fillC2<<<NBUK_USED, 1024, 0, stream>>>(ebuf, bbase, row_ptr, csr_src);
    k_agg1<<<N_NODES / 8, 256, 0, stream>>>(row_ptr, csr_src, x_h, agg_h);
    k_gemm1<<<(N_NODES + 63) / 64, 256, 0, stream>>>(agg_h, row_ptr, x_h,
                                                     W1lf, b1l, W1rf,
                                                     gamma, beta, mean, var, h_h);
    k_gemm2<<<(N_NODES + 63) / 64, 256, 0, stream>>>(h_h, W2f, b2l, p2, out);
    k_agg2<<<N_NODES / 16, 256, 0, stream>>>(row_ptr, csr_src, p2, out);
}